// Round 3
// baseline (1006.134 us; speedup 1.0000x reference)
//
#include <hip/hip_runtime.h>
#include <hip/hip_bf16.h>
#include <stdint.h>

typedef short bf16x8 __attribute__((ext_vector_type(8)));
typedef float f32x4 __attribute__((ext_vector_type(4)));
typedef unsigned short u16;

#define B_   2
#define S_   4096
#define H_   2048
#define HD_  128
#define M2_  8192              // B*S
#define WELEMS (H_*H_)         // 4194304 per weight

__device__ __forceinline__ u16 f2bf(float f) {
  union { float f; uint32_t u; } v; v.f = f;
  uint32_t u = v.u;
  u += 0x7FFFu + ((u >> 16) & 1u);     // round-to-nearest-even
  return (u16)(u >> 16);
}
__device__ __forceinline__ float bf2f(u16 h) {
  union { uint32_t u; float f; } v; v.u = ((uint32_t)h) << 16;
  return v.f;
}

// async global->LDS, 16B per lane (bf16 operands only)
__device__ __forceinline__ void gload16(const void* gptr, const void* lptr) {
  __builtin_amdgcn_global_load_lds(
      (const __attribute__((address_space(1))) void*)(uintptr_t)gptr,
      (__attribute__((address_space(3))) void*)(uint32_t)(uintptr_t)lptr,
      16, 0, 0);
}

// ---------------------------------------------------------------------------
// BT GEMM: C[m][n] = sum_k A[m][k] * B[n][k].
// A: [M][K] bf16 (AF32=0) or fp32 (AF32=1, cast to bf16 during LDS staging).
// B: [N][K] bf16, staged via global_load_lds.
// Epilogue multiplies acc by *scale (fp32) if scale != nullptr.
// EPI: 0 = bf16 store (ldc), 1 = transposed bf16 store C[n][m] (ldc = M
//      stride of the transposed buffer), 2 = fp32 store.
// 128x128 tile, BK=32, 4 waves (2x2) of 64x64 each.
// ---------------------------------------------------------------------------
template<int EPI, int AF32>
__global__ __launch_bounds__(256, 2)
void gemm_bt(const void* __restrict__ Av, const u16* __restrict__ B,
             void* __restrict__ Cv, int K, int ldc,
             const float* __restrict__ scale)
{
  __shared__ u16 As[128*32];
  __shared__ u16 Bs[128*32];

  const int tid  = threadIdx.x;
  const int lane = tid & 63;
  const int wr   = (tid >> 7) & 1;
  const int wc   = (tid >> 6) & 1;
  const int fr   = lane & 15;
  const int fq   = lane >> 4;

  const int brow = blockIdx.y << 7;
  const int bcol = blockIdx.x << 7;

  const int arow = brow + (tid >> 2);
  const int acol = (tid & 3) * 8;

  const u16*   Ag  = (const u16*)Av   + (size_t)arow*K + acol;   // AF32=0
  const float* Ag32= (const float*)Av + (size_t)arow*K + acol;   // AF32=1
  const u16*   Bg  = B + (size_t)(bcol + (tid>>2))*K + acol;
  const size_t rowhalf = (size_t)64*K;

  u16* Asd = As + tid*8;      // linear, 16B per thread
  u16* Bsd = Bs + tid*8;

  f32x4 acc[4][4];
  #pragma unroll
  for (int m=0;m<4;++m)
    #pragma unroll
    for (int n=0;n<4;++n) acc[m][n] = (f32x4){0.f,0.f,0.f,0.f};

  const u16* ap0 = &As[((wr<<6) + fr)*32 + (fq<<3)];
  const u16* bp0 = &Bs[((wc<<6) + fr)*32 + (fq<<3)];

  for (int kt = 0; kt < K; kt += 32) {
    if constexpr (AF32) {
      // fp32 A -> bf16 LDS (reg staging)
      union { bf16x8 v; u16 h[8]; } p0, p1;
      float4 x0 = *(const float4*)(Ag32);
      float4 x1 = *(const float4*)(Ag32 + 4);
      float4 y0 = *(const float4*)(Ag32 + rowhalf);
      float4 y1 = *(const float4*)(Ag32 + rowhalf + 4);
      p0.h[0]=f2bf(x0.x); p0.h[1]=f2bf(x0.y); p0.h[2]=f2bf(x0.z); p0.h[3]=f2bf(x0.w);
      p0.h[4]=f2bf(x1.x); p0.h[5]=f2bf(x1.y); p0.h[6]=f2bf(x1.z); p0.h[7]=f2bf(x1.w);
      p1.h[0]=f2bf(y0.x); p1.h[1]=f2bf(y0.y); p1.h[2]=f2bf(y0.z); p1.h[3]=f2bf(y0.w);
      p1.h[4]=f2bf(y1.x); p1.h[5]=f2bf(y1.y); p1.h[6]=f2bf(y1.z); p1.h[7]=f2bf(y1.w);
      *(bf16x8*)(Asd)        = p0.v;
      *(bf16x8*)(Asd + 2048) = p1.v;
      Ag32 += 32;
    } else {
      gload16(Ag,           Asd);
      gload16(Ag + rowhalf, Asd + 2048);
      Ag += 32;
    }
    gload16(Bg,           Bsd);
    gload16(Bg + rowhalf, Bsd + 2048);
    Bg += 32;
    __syncthreads();

    bf16x8 av[4], bv[4];
    #pragma unroll
    for (int m=0;m<4;++m) av[m] = *(const bf16x8*)(ap0 + m*(16*32));
    #pragma unroll
    for (int n=0;n<4;++n) bv[n] = *(const bf16x8*)(bp0 + n*(16*32));
    #pragma unroll
    for (int m=0;m<4;++m)
      #pragma unroll
      for (int n=0;n<4;++n)
        acc[m][n] = __builtin_amdgcn_mfma_f32_16x16x32_bf16(av[m], bv[n], acc[m][n], 0, 0, 0);
    __syncthreads();
  }

  const float sc = scale ? *scale : 1.0f;

  // C/D layout (m89-verified): col = lane&15, row = (lane>>4)*4 + reg
  if constexpr (EPI == 0) {
    u16* C = (u16*)Cv;
    #pragma unroll
    for (int m=0;m<4;++m) {
      const int r0 = brow + (wr<<6) + (m<<4) + (fq<<2);
      #pragma unroll
      for (int n=0;n<4;++n) {
        const int c = bcol + (wc<<6) + (n<<4) + fr;
        #pragma unroll
        for (int j=0;j<4;++j)
          C[(size_t)(r0+j)*ldc + c] = f2bf(acc[m][n][j]*sc);
      }
    }
  } else if constexpr (EPI == 1) {
    // transposed store: C[n][m] with row stride ldc; 4 consecutive m = 8B
    u16* C = (u16*)Cv;
    #pragma unroll
    for (int m=0;m<4;++m) {
      const int r0 = brow + (wr<<6) + (m<<4) + (fq<<2);
      #pragma unroll
      for (int n=0;n<4;++n) {
        const int c = bcol + (wc<<6) + (n<<4) + fr;
        ushort4 pk;
        pk.x = f2bf(acc[m][n][0]*sc);
        pk.y = f2bf(acc[m][n][1]*sc);
        pk.z = f2bf(acc[m][n][2]*sc);
        pk.w = f2bf(acc[m][n][3]*sc);
        *(ushort4*)&C[(size_t)c*ldc + r0] = pk;
      }
    }
  } else {
    float* C = (float*)Cv;
    #pragma unroll
    for (int m=0;m<4;++m) {
      const int r0 = brow + (wr<<6) + (m<<4) + (fq<<2);
      #pragma unroll
      for (int n=0;n<4;++n) {
        const int c = bcol + (wc<<6) + (n<<4) + fr;
        #pragma unroll
        for (int j=0;j<4;++j)
          C[(size_t)(r0+j)*ldc + c] = acc[m][n][j]*sc;
      }
    }
  }
}

// ---------------------------------------------------------------------------
// bitlinear scale: two-stage deterministic mean(|w|)
// ---------------------------------------------------------------------------
__global__ __launch_bounds__(256)
void abssum_partial(const float* __restrict__ w0, const float* __restrict__ w1,
                    const float* __restrict__ w2, const float* __restrict__ w3,
                    float* __restrict__ part)
{
  const float* w = (blockIdx.y==0)?w0:(blockIdx.y==1)?w1:(blockIdx.y==2)?w2:w3;
  float s = 0.f;
  const int N4 = WELEMS/4;
  for (int i = blockIdx.x*256 + threadIdx.x; i < N4; i += 256*256) {
    float4 v = ((const float4*)w)[i];
    s += fabsf(v.x)+fabsf(v.y)+fabsf(v.z)+fabsf(v.w);
  }
  #pragma unroll
  for (int o=32;o;o>>=1) s += __shfl_xor(s,o);
  __shared__ float r[4];
  if ((threadIdx.x&63)==0) r[threadIdx.x>>6] = s;
  __syncthreads();
  if (threadIdx.x==0) part[blockIdx.y*256 + blockIdx.x] = (r[0]+r[1])+(r[2]+r[3]);
}

__global__ __launch_bounds__(256)
void scale_final(const float* __restrict__ part, float* __restrict__ scales)
{
  float s = part[blockIdx.x*256 + threadIdx.x];
  #pragma unroll
  for (int o=32;o;o>>=1) s += __shfl_xor(s,o);
  __shared__ float r[4];
  if ((threadIdx.x&63)==0) r[threadIdx.x>>6] = s;
  __syncthreads();
  if (threadIdx.x==0) scales[blockIdx.x] = ((r[0]+r[1])+(r[2]+r[3])) * (1.f/(float)WELEMS);
}

// ternary quantization: store exact {-1,0,+1} in bf16; scale applied later
__global__ __launch_bounds__(256)
void dequant_w(const float* __restrict__ w0, const float* __restrict__ w1,
               const float* __restrict__ w2, const float* __restrict__ w3,
               const float* __restrict__ scales, u16* __restrict__ out)
{
  const int wi = blockIdx.y;
  const float* w = (wi==0)?w0:(wi==1)?w1:(wi==2)?w2:w3;
  u16* o = out + (size_t)wi * WELEMS;
  const float inv = 1.f/(scales[wi] + 1e-5f);
  const int i0 = (blockIdx.x*256 + threadIdx.x)*8;
  float4 a = *(const float4*)(w + i0);
  float4 b = *(const float4*)(w + i0 + 4);
  float t[8] = {a.x,a.y,a.z,a.w,b.x,b.y,b.z,b.w};
  union { uint4 v; u16 h[8]; } r;
  #pragma unroll
  for (int j=0;j<8;++j){
    float x = t[j]*inv;
    x = fminf(fmaxf(x,-1.f),1.f);
    r.h[j] = f2bf(rintf(x));        // exact ternary in bf16
  }
  *(uint4*)(o + i0) = r.v;
}

// in-place RoPE on Q and K (pair d, d+64 within each 128-dim head chunk)
__global__ __launch_bounds__(256)
void rope_qk(u16* __restrict__ Q, u16* __restrict__ K,
             const float* __restrict__ cosb, const float* __restrict__ sinb)
{
  const uint32_t idx = blockIdx.x*256 + threadIdx.x;   // < 2*4096*16*64
  const int d   = idx & 63;
  const int h16 = (idx >> 6) & 15;
  const int s   = (idx >> 10) & (S_-1);
  const int b   = idx >> 22;
  const size_t base = ((size_t)b*S_ + s)*H_ + h16*HD_ + d;
  const int ci = s*HD_ + d;
  const float c0 = cosb[ci], c1 = cosb[ci+64];
  const float s0 = sinb[ci], s1 = sinb[ci+64];
  const float q0 = bf2f(Q[base]), q1 = bf2f(Q[base+64]);
  Q[base]    = f2bf(q0*c0 - q1*s0);
  Q[base+64] = f2bf(q1*c1 + q0*s1);
  const float k0 = bf2f(K[base]), k1 = bf2f(K[base+64]);
  K[base]    = f2bf(k0*c0 - k1*s0);
  K[base+64] = f2bf(k1*c1 + k0*s1);
}

// fp32 row softmax over S_=4096, in place; applies 1/sqrt(HD) + mask
__global__ __launch_bounds__(256)
void softmax_rows_f32(float* __restrict__ P, const float* __restrict__ mask)
{
  const int row = blockIdx.x;            // 0..S_-1 (per-batch launch)
  float* prow = P + (size_t)row * S_;
  const float* mrow = mask + (size_t)row * S_;
  const int tid  = threadIdx.x;
  const int lane = tid & 63;
  const int base = tid * 16;

  float v[16];
  #pragma unroll
  for (int j=0;j<4;++j) ((float4*)v)[j] = *(const float4*)(prow + base + 4*j);
  float mk[16];
  #pragma unroll
  for (int j=0;j<4;++j) ((float4*)mk)[j] = *(const float4*)(mrow + base + 4*j);

  const float sc = 0.08838834764831845f;  // 1/sqrt(128)
  #pragma unroll
  for (int i=0;i<16;++i) v[i] = v[i]*sc + mk[i];

  float mx = v[0];
  #pragma unroll
  for (int i=1;i<16;++i) mx = fmaxf(mx, v[i]);
  #pragma unroll
  for (int o=32;o;o>>=1) mx = fmaxf(mx, __shfl_xor(mx, o));
  __shared__ float red[8];
  if (lane==0) red[tid>>6] = mx;
  __syncthreads();
  mx = fmaxf(fmaxf(red[0],red[1]), fmaxf(red[2],red[3]));

  float e[16]; float sm = 0.f;
  #pragma unroll
  for (int i=0;i<16;++i){ e[i] = __expf(v[i]-mx); sm += e[i]; }
  #pragma unroll
  for (int o=32;o;o>>=1) sm += __shfl_xor(sm, o);
  if (lane==0) red[4 + (tid>>6)] = sm;
  __syncthreads();
  sm = (red[4]+red[5])+(red[6]+red[7]);
  const float inv = 1.f/sm;

  #pragma unroll
  for (int i=0;i<16;++i) v[i] = e[i]*inv;
  #pragma unroll
  for (int j=0;j<4;++j) *(float4*)(prow + base + 4*j) = ((float4*)v)[j];
}

__global__ void fill_f32(float* p, float v, int n) {
  int i = blockIdx.x*256 + threadIdx.x;
  if (i < n) p[i] = v;
}

// ---------------------------------------------------------------------------
extern "C" void kernel_launch(void* const* d_in, const int* in_sizes, int n_in,
                              void* d_out, int out_size, void* d_ws, size_t ws_size,
                              hipStream_t stream)
{
  const float* hs   = (const float*)d_in[0];
  const float* mask = (const float*)d_in[1];
  const float* cosb = (const float*)d_in[2];
  const float* sinb = (const float*)d_in[3];
  const float* wq   = (const float*)d_in[4];
  const float* wk   = (const float*)d_in[5];
  const float* wv   = (const float*)d_in[6];
  const float* wo   = (const float*)d_in[7];

  // ws layout (112 MiB + 8 KB):
  //   s0 [0,32M)    : Wb — 4 ternary weights, bf16 (live whole call)
  //   s1 [32M,64M)  : Q (both batches) -> AO0/AO1 overwrite Q0/Q1 after use
  //   s2 [64M,96M)  : K (both batches)
  //   s3 [96M,112M) : Vt for CURRENT batch, [H_][S_] bf16 (16 MiB)
  //   [112M,+8K)    : part (4KB) + scales[4]
  // fp32 scores/probs for the current batch live in d_out (64 MiB exactly).
  char* w = (char*)d_ws;
  const size_t SZ = (size_t)M2_ * H_ * 2;   // 32 MiB
  u16* Wb = (u16*)(w);
  u16* Qb = (u16*)(w + SZ);
  u16* Kb = (u16*)(w + 2*SZ);
  u16* Vt = (u16*)(w + 3*SZ);               // 16 MiB used
  float* part   = (float*)(w + 3*SZ + SZ/2);
  float* scales = part + 1024;
  u16*   AO = Qb;                           // alias (per-batch halves)
  float* Sf = (float*)d_out;                // per-batch fp32 scores/probs

  const size_t need = 3*SZ + SZ/2 + 8192;
  if (ws_size < need || out_size != M2_*H_) {
    float v = (out_size != M2_*H_) ? 2.0e9f : (float)ws_size;
    fill_f32<<<dim3((out_size+255)/256), dim3(256), 0, stream>>>((float*)d_out, v, out_size);
    return;
  }

  dim3 blk(256);
  const size_t QOFF = (size_t)S_*H_;        // per-batch elems in Q/K/AO

  abssum_partial<<<dim3(256,4), blk, 0, stream>>>(wq,wk,wv,wo, part);
  scale_final  <<<dim3(4),     blk, 0, stream>>>(part, scales);
  dequant_w    <<<dim3(WELEMS/(256*8),4), blk, 0, stream>>>(wq,wk,wv,wo, scales, Wb);

  // Q = (X @ Wq_tern^T)*sq ; K = (X @ Wk_tern^T)*sk   (fp32 A fused-cast)
  gemm_bt<0,1><<<dim3(16,64), blk, 0, stream>>>(hs, Wb,        Qb, H_, H_, &scales[0]);
  gemm_bt<0,1><<<dim3(16,64), blk, 0, stream>>>(hs, Wb+WELEMS, Kb, H_, H_, &scales[1]);

  rope_qk<<<dim3((B_*S_*16*64)/256), blk, 0, stream>>>(Qb, Kb, cosb, sinb);

  for (int b = 0; b < B_; ++b) {
    // scores (fp32) = Qb @ Kb^T : M=N=4096, K=2048
    gemm_bt<2,0><<<dim3(32,32), blk, 0, stream>>>(Qb + b*QOFF, Kb + b*QOFF,
                                                  Sf, H_, S_, nullptr);
    softmax_rows_f32<<<dim3(S_), blk, 0, stream>>>(Sf, mask);

    // Vt = ((X_b @ Wv_tern^T)*sv)^T : [h][tok], M=4096 rows of batch b
    gemm_bt<1,1><<<dim3(16,32), blk, 0, stream>>>(hs + (size_t)b*QOFF, Wb+2*WELEMS,
                                                  Vt, H_, S_, &scales[2]);

    // AO_b = probs(fp32, fused-cast) @ Vt : M=4096, N=2048, K=4096
    gemm_bt<0,1><<<dim3(16,32), blk, 0, stream>>>(Sf, Vt, AO + b*QOFF,
                                                  S_, H_, nullptr);
  }

  // out = (AO @ Wo_tern^T)*so (fp32): M=8192, N=2048, K=2048
  gemm_bt<2,0><<<dim3(16,64), blk, 0, stream>>>(AO, Wb+3*WELEMS, d_out, H_, H_, &scales[3]);
}

// Round 4
// 602.080 us; speedup vs baseline: 1.6711x; 1.6711x over previous
//
#include <hip/hip_runtime.h>
#include <hip/hip_bf16.h>
#include <stdint.h>

typedef _Float16 f16x8 __attribute__((ext_vector_type(8)));
typedef float f32x4 __attribute__((ext_vector_type(4)));
typedef unsigned short u16;

#define B_   2
#define S_   4096
#define H_   2048
#define M2_  8192              // B*S
#define WELEMS (H_*H_)         // 4194304 per weight

__device__ __forceinline__ u16 f2h(float f) {
  _Float16 h = (_Float16)f;                 // v_cvt_f16_f32, RNE
  return __builtin_bit_cast(unsigned short, h);
}
__device__ __forceinline__ float h2f(u16 b) {
  _Float16 h = __builtin_bit_cast(_Float16, b);
  return (float)h;
}

// async global->LDS, 16B per lane; dest = wave-uniform base + lane*16
__device__ __forceinline__ void gload16(const void* gptr, const void* lptr) {
  __builtin_amdgcn_global_load_lds(
      (const __attribute__((address_space(1))) void*)(uintptr_t)gptr,
      (__attribute__((address_space(3))) void*)(uint32_t)(uintptr_t)lptr,
      16, 0, 0);
}

// ---------------------------------------------------------------------------
// 256x256-tile BT GEMM, fp16 MFMA: C[m][n] = sum_k A[m][k]*B[n][k].
// BK=32, ring-4 LDS double... quad-buffer (128 KiB), prefetch distance 2,
// counted vmcnt(4), 2 phases/tile {8|4 ds_read_b128, 2 gload_lds, barrier,
// lgkmcnt(0), setprio(1), 16 MFMA, setprio(0)}, XOR-swizzled LDS via
// pre-swizzled global source (linear gload_lds dest).
// 512 threads = 8 waves (2M x 4N), per-wave 128x64 out, acc f32x4[8][4].
// EPI: 0 = fp16 C[m][n]*cs; 1 = fp16 transposed C[n][m]*cs; 2 = fp32*cs.
// ---------------------------------------------------------------------------
template<int EPI>
__global__ __launch_bounds__(512, 2)
void gemm8(const u16* __restrict__ A, const u16* __restrict__ B,
           void* __restrict__ Cv, int K, int ldc, float cscale,
           long long sA, long long sB, long long sC)
{
  extern __shared__ char smem[];            // 131072 B: A [0,64K), B [64K,128K)
  const int tid  = threadIdx.x;
  const int lane = tid & 63;
  const int wid  = tid >> 6;
  const int wm   = wid >> 2;                // 0..1
  const int wn   = wid & 3;                 // 0..3

  // XCD-bijective swizzle of flat block id within z-slice (nwg % 8 == 0)
  const int gx  = gridDim.x;
  const int nwg = gx * gridDim.y;
  int f = blockIdx.y * gx + blockIdx.x;
  f = (f & 7) * (nwg >> 3) + (f >> 3);
  const int brow = (f / gx) << 8;
  const int bcol = (f % gx) << 8;
  const int z    = blockIdx.z;

  const u16* Ab = A + (size_t)z * sA;
  const u16* Bb = B + (size_t)z * sB;

  // staging: thread t supplies LDS-linear bytes t*16; global src pre-swizzled:
  // row = 2*(t>>3) + ((t>>2)&1)  (+128 per 2nd issue), k8 = (t&3) ^ ((t>>3)&3)
  const int srow = ((tid >> 3) << 1) | ((tid >> 2) & 1);
  const int sk8  = (tid & 3) ^ ((tid >> 3) & 3);
  const u16* gA0 = Ab + (size_t)(brow + srow) * K + sk8 * 8;
  const u16* gA1 = gA0 + (size_t)128 * K;
  const u16* gB0 = Bb + (size_t)(bcol + srow) * K + sk8 * 8;
  const u16* gB1 = gB0 + (size_t)128 * K;

  char* ldsAw = smem + tid * 16;            // linear write dest (A region)
  char* ldsBw = ldsAw + 65536;              // B region

  // read side: byte(r,k8) = (r>>1)*128 + ((k8 ^ ((r>>1)&3))<<4) + ((r&1)<<6)
  const int l15 = lane & 15;
  const int lanepart = ((l15 >> 1) << 7) |
                       ((((lane >> 4) ^ ((l15 >> 1) & 3))) << 4) |
                       ((lane & 1) << 6);
  const char* ldsA = smem + (wm << 13) + lanepart;           // + wm*8192
  const char* ldsB = smem + 65536 + (wn << 12) + lanepart;   // + wn*4096

  f32x4 acc[8][4];
  #pragma unroll
  for (int i = 0; i < 8; ++i)
    #pragma unroll
    for (int j = 0; j < 4; ++j) acc[i][j] = (f32x4){0.f, 0.f, 0.f, 0.f};

#define DS_A(BUF, MH, MR) (*(const f16x8*)(ldsA + (BUF)*16384 + (MH)*4096 + (MR)*1024))
#define DS_B(BUF, NR)     (*(const f16x8*)(ldsB + (BUF)*16384 + (NR)*1024))

#define MFMA4(AM, AV) \
  acc[AM][0] = __builtin_amdgcn_mfma_f32_16x16x32_f16(AV, b0, acc[AM][0], 0, 0, 0); \
  acc[AM][1] = __builtin_amdgcn_mfma_f32_16x16x32_f16(AV, b1, acc[AM][1], 0, 0, 0); \
  acc[AM][2] = __builtin_amdgcn_mfma_f32_16x16x32_f16(AV, b2, acc[AM][2], 0, 0, 0); \
  acc[AM][3] = __builtin_amdgcn_mfma_f32_16x16x32_f16(AV, b3, acc[AM][3], 0, 0, 0);

#define TILE(BUF, IBUF, DOISS, LASTT) do {                                    \
    if (LASTT) { asm volatile("s_waitcnt vmcnt(0)" ::: "memory"); }           \
    else       { asm volatile("s_waitcnt vmcnt(4)" ::: "memory"); }           \
    __builtin_amdgcn_s_barrier();                                             \
    if (DOISS) {                                                              \
      gload16(gA0, ldsAw + (IBUF)*16384);                                     \
      gload16(gA1, ldsAw + (IBUF)*16384 + 8192);                              \
    }                                                                         \
    f16x8 b0 = DS_B(BUF,0), b1 = DS_B(BUF,1), b2 = DS_B(BUF,2), b3 = DS_B(BUF,3); \
    f16x8 a0 = DS_A(BUF,0,0), a1 = DS_A(BUF,0,1), a2 = DS_A(BUF,0,2), a3 = DS_A(BUF,0,3); \
    asm volatile("s_waitcnt lgkmcnt(0)" ::: "memory");                        \
    __builtin_amdgcn_sched_barrier(0);                                        \
    __builtin_amdgcn_s_setprio(1);                                            \
    MFMA4(0, a0) MFMA4(1, a1) MFMA4(2, a2) MFMA4(3, a3)                       \
    __builtin_amdgcn_s_setprio(0);                                            \
    __builtin_amdgcn_s_barrier();                                             \
    if (DOISS) {                                                              \
      gload16(gB0, ldsBw + (IBUF)*16384);                                     \
      gload16(gB1, ldsBw + (IBUF)*16384 + 8192);                              \
      gA0 += 32; gA1 += 32; gB0 += 32; gB1 += 32;                             \
    }                                                                         \
    a0 = DS_A(BUF,1,0); a1 = DS_A(BUF,1,1); a2 = DS_A(BUF,1,2); a3 = DS_A(BUF,1,3); \
    asm volatile("s_waitcnt lgkmcnt(0)" ::: "memory");                        \
    __builtin_amdgcn_sched_barrier(0);                                        \
    __builtin_amdgcn_s_setprio(1);                                            \
    MFMA4(4, a0) MFMA4(5, a1) MFMA4(6, a2) MFMA4(7, a3)                       \
    __builtin_amdgcn_s_setprio(0);                                            \
  } while (0)

  // prologue: stage tiles 0 and 1 (issue order per tile: A,A,B,B)
  gload16(gA0, ldsAw);          gload16(gA1, ldsAw + 8192);
  gload16(gB0, ldsBw);          gload16(gB1, ldsBw + 8192);
  gA0 += 32; gA1 += 32; gB0 += 32; gB1 += 32;
  gload16(gA0, ldsAw + 16384);  gload16(gA1, ldsAw + 16384 + 8192);
  gload16(gB0, ldsBw + 16384);  gload16(gB1, ldsBw + 16384 + 8192);
  gA0 += 32; gA1 += 32; gB0 += 32; gB1 += 32;

  const int NT4 = K >> 7;                   // (K/32)/4, K multiple of 128
  for (int it = 0; it < NT4; ++it) {
    const bool lst = (it == NT4 - 1);
    TILE(0, 2, true,  false);
    TILE(1, 3, true,  false);
    TILE(2, 0, !lst,  false);
    TILE(3, 1, !lst,  lst);
  }

#undef TILE
#undef MFMA4
#undef DS_A
#undef DS_B

  // C/D layout: col = lane&15, row = (lane>>4)*4 + reg
  const float scv = cscale;
  const int cr0 = brow + (wm << 7) + ((lane >> 4) << 2);
  const int cc0 = bcol + (wn << 6) + l15;

  if constexpr (EPI == 0) {                 // fp16 store
    u16* C = (u16*)Cv + (size_t)z * sC;
    #pragma unroll
    for (int am = 0; am < 8; ++am) {
      const int r = cr0 + am * 16;
      #pragma unroll
      for (int an = 0; an < 4; ++an) {
        const int c = cc0 + an * 16;
        #pragma unroll
        for (int j = 0; j < 4; ++j)
          C[(size_t)(r + j) * ldc + c] = f2h(acc[am][an][j] * scv);
      }
    }
  } else if constexpr (EPI == 1) {          // fp16 transposed store C[n][m]
    u16* C = (u16*)Cv + (size_t)z * sC;
    #pragma unroll
    for (int am = 0; am < 8; ++am) {
      const int r = cr0 + am * 16;
      #pragma unroll
      for (int an = 0; an < 4; ++an) {
        const int c = cc0 + an * 16;
        ushort4 pk;
        pk.x = f2h(acc[am][an][0] * scv);
        pk.y = f2h(acc[am][an][1] * scv);
        pk.z = f2h(acc[am][an][2] * scv);
        pk.w = f2h(acc[am][an][3] * scv);
        *(ushort4*)&C[(size_t)c * ldc + r] = pk;
      }
    }
  } else {                                  // fp32 store
    float* C = (float*)Cv + (size_t)z * sC;
    #pragma unroll
    for (int am = 0; am < 8; ++am) {
      const int r = cr0 + am * 16;
      #pragma unroll
      for (int an = 0; an < 4; ++an) {
        const int c = cc0 + an * 16;
        #pragma unroll
        for (int j = 0; j < 4; ++j)
          C[(size_t)(r + j) * ldc + c] = acc[am][an][j] * scv;
      }
    }
  }
}

// ---------------------------------------------------------------------------
// bitlinear scale: two-stage deterministic mean(|w|)
// ---------------------------------------------------------------------------
__global__ __launch_bounds__(256)
void abssum_partial(const float* __restrict__ w0, const float* __restrict__ w1,
                    const float* __restrict__ w2, const float* __restrict__ w3,
                    float* __restrict__ part)
{
  const float* w = (blockIdx.y==0)?w0:(blockIdx.y==1)?w1:(blockIdx.y==2)?w2:w3;
  float s = 0.f;
  const int N4 = WELEMS/4;
  for (int i = blockIdx.x*256 + threadIdx.x; i < N4; i += 256*256) {
    float4 v = ((const float4*)w)[i];
    s += fabsf(v.x)+fabsf(v.y)+fabsf(v.z)+fabsf(v.w);
  }
  #pragma unroll
  for (int o=32;o;o>>=1) s += __shfl_xor(s,o);
  __shared__ float r[4];
  if ((threadIdx.x&63)==0) r[threadIdx.x>>6] = s;
  __syncthreads();
  if (threadIdx.x==0) part[blockIdx.y*256 + blockIdx.x] = (r[0]+r[1])+(r[2]+r[3]);
}

__global__ __launch_bounds__(256)
void scale_final(const float* __restrict__ part, float* __restrict__ scales)
{
  float s = part[blockIdx.x*256 + threadIdx.x];
  #pragma unroll
  for (int o=32;o;o>>=1) s += __shfl_xor(s,o);
  __shared__ float r[4];
  if ((threadIdx.x&63)==0) r[threadIdx.x>>6] = s;
  __syncthreads();
  if (threadIdx.x==0) scales[blockIdx.x] = ((r[0]+r[1])+(r[2]+r[3])) * (1.f/(float)WELEMS);
}

// ternary quant + fp16 dequant: w -> rint(clip(w/(s+eps)))*s, stored fp16
__global__ __launch_bounds__(256)
void dequant_w(const float* __restrict__ w0, const float* __restrict__ w1,
               const float* __restrict__ w2, const float* __restrict__ w3,
               const float* __restrict__ scales, u16* __restrict__ out)
{
  const int wi = blockIdx.y;
  const float* w = (wi==0)?w0:(wi==1)?w1:(wi==2)?w2:w3;
  u16* o = out + (size_t)wi * WELEMS;
  const float scv = scales[wi];
  const float inv = 1.f/(scv + 1e-5f);
  const int i0 = (blockIdx.x*256 + threadIdx.x)*8;
  float4 a = *(const float4*)(w + i0);
  float4 b = *(const float4*)(w + i0 + 4);
  float t[8] = {a.x,a.y,a.z,a.w,b.x,b.y,b.z,b.w};
  union { uint4 v; u16 h[8]; } r;
  #pragma unroll
  for (int j=0;j<8;++j){
    float x = t[j]*inv;
    x = fminf(fmaxf(x,-1.f),1.f);
    r.h[j] = f2h(rintf(x)*scv);
  }
  *(uint4*)(o + i0) = r.v;
}

__global__ __launch_bounds__(256)
void cast_f16(const float* __restrict__ x, u16* __restrict__ o)
{
  const int i0 = (blockIdx.x*256 + threadIdx.x)*8;
  float4 a = *(const float4*)(x + i0);
  float4 b = *(const float4*)(x + i0 + 4);
  float t[8] = {a.x,a.y,a.z,a.w,b.x,b.y,b.z,b.w};
  union { uint4 v; u16 h[8]; } r;
  #pragma unroll
  for (int j=0;j<8;++j) r.h[j] = f2h(t[j]);
  *(uint4*)(o + i0) = r.v;
}

// in-place RoPE on fp16 Q and K (pair d, d+64 within each 128-dim chunk)
__global__ __launch_bounds__(256)
void rope_qk(u16* __restrict__ Q, u16* __restrict__ K,
             const float* __restrict__ cosb, const float* __restrict__ sinb)
{
  const uint32_t idx = blockIdx.x*256 + threadIdx.x;   // < 2*4096*16*64
  const int d   = idx & 63;
  const int h16 = (idx >> 6) & 15;
  const int s   = (idx >> 10) & (S_-1);
  const int b   = idx >> 22;
  const size_t base = ((size_t)b*S_ + s)*H_ + h16*128 + d;
  const int ci = s*128 + d;
  const float c0 = cosb[ci], c1 = cosb[ci+64];
  const float s0 = sinb[ci], s1 = sinb[ci+64];
  const float q0 = h2f(Q[base]), q1 = h2f(Q[base+64]);
  Q[base]    = f2h(q0*c0 - q1*s0);
  Q[base+64] = f2h(q1*c1 + q0*s1);
  const float k0 = h2f(K[base]), k1 = h2f(K[base+64]);
  K[base]    = f2h(k0*c0 - k1*s0);
  K[base+64] = f2h(k1*c1 + k0*s1);
}

// row softmax over S_=4096, in place on fp16 scores (scale already applied);
// adds mask, writes fp16 probs
__global__ __launch_bounds__(256)
void softmax_h(u16* __restrict__ P, const float* __restrict__ mask)
{
  const int row = blockIdx.x;               // 0..B_*S_-1
  const int q   = row & (S_-1);
  u16* prow = P + (size_t)row * S_;
  const float* mrow = mask + (size_t)q * S_;
  const int tid  = threadIdx.x;
  const int lane = tid & 63;
  const int base = tid * 16;

  union { uint4 v[2]; u16 h[16]; } sv;
  sv.v[0] = *(const uint4*)(prow + base);
  sv.v[1] = *(const uint4*)(prow + base + 8);
  float mk[16];
  #pragma unroll
  for (int j=0;j<4;++j) ((float4*)mk)[j] = *(const float4*)(mrow + base + 4*j);

  float v[16];
  #pragma unroll
  for (int i=0;i<16;++i) v[i] = h2f(sv.h[i]) + mk[i];

  float mx = v[0];
  #pragma unroll
  for (int i=1;i<16;++i) mx = fmaxf(mx, v[i]);
  #pragma unroll
  for (int o=32;o;o>>=1) mx = fmaxf(mx, __shfl_xor(mx, o));
  __shared__ float red[8];
  if (lane==0) red[tid>>6] = mx;
  __syncthreads();
  mx = fmaxf(fmaxf(red[0],red[1]), fmaxf(red[2],red[3]));

  float e[16]; float sm = 0.f;
  #pragma unroll
  for (int i=0;i<16;++i){ e[i] = __expf(v[i]-mx); sm += e[i]; }
  #pragma unroll
  for (int o=32;o;o>>=1) sm += __shfl_xor(sm, o);
  if (lane==0) red[4 + (tid>>6)] = sm;
  __syncthreads();
  sm = (red[4]+red[5])+(red[6]+red[7]);
  const float inv = 1.f/sm;

  union { uint4 v[2]; u16 h[16]; } ov;
  #pragma unroll
  for (int i=0;i<16;++i) ov.h[i] = f2h(e[i]*inv);
  *(uint4*)(prow + base)     = ov.v[0];
  *(uint4*)(prow + base + 8) = ov.v[1];
}

__global__ void fill_f32(float* p, float v, int n) {
  int i = blockIdx.x*256 + threadIdx.x;
  if (i < n) p[i] = v;
}

// ---------------------------------------------------------------------------
extern "C" void kernel_launch(void* const* d_in, const int* in_sizes, int n_in,
                              void* d_out, int out_size, void* d_ws, size_t ws_size,
                              hipStream_t stream)
{
  const float* hs   = (const float*)d_in[0];
  const float* mask = (const float*)d_in[1];
  const float* cosb = (const float*)d_in[2];
  const float* sinb = (const float*)d_in[3];
  const float* wq   = (const float*)d_in[4];
  const float* wk   = (const float*)d_in[5];
  const float* wv   = (const float*)d_in[6];
  const float* wo   = (const float*)d_in[7];

  // ws layout, 128 MiB exactly (lifetime aliasing):
  //   Wh [0,32M)   : 4 pre-scaled ternary weights, fp16    (live whole call)
  //   Xh [32,64M)  : hidden_states fp16                    (dead after Vt)
  //   Qh [64,96M)  : Q fp16 -> AO (PV output) per batch
  //   Kh [96,128M) : K fp16 -> Vt[b][h][tok] per batch
  // d_out: part/scales (head, pre-GEMM) -> fp16 scores/probs both batches
  //        (64 MiB exactly) -> final fp32 output.
  char* w = (char*)d_ws;
  const size_t SZ = (size_t)M2_ * H_ * 2;   // 32 MiB
  u16* Wh = (u16*)(w);
  u16* Xh = (u16*)(w + SZ);
  u16* Qh = (u16*)(w + 2*SZ);
  u16* Kh = (u16*)(w + 3*SZ);
  u16* AO = Qh;                              // alias after QK^T
  u16* Vt = Kh;                              // alias after QK^T
  float* part   = (float*)d_out;             // dead before scores written
  float* scales = part + 1024;
  u16* P  = (u16*)d_out;                     // fp16 scores/probs, both batches

  const size_t need = 4*SZ;                  // 134,217,728 B
  if (ws_size < need || out_size != M2_*H_) {
    float v = (out_size != M2_*H_) ? 2.0e9f : (float)ws_size;
    fill_f32<<<dim3((out_size+255)/256), dim3(256), 0, stream>>>((float*)d_out, v, out_size);
    return;
  }

  dim3 blk(256), gblk(512);
  const size_t QOFF = (size_t)S_*H_;         // per-batch elems
  const float qksc = 0.08838834764831845f;   // 1/sqrt(128)

  abssum_partial<<<dim3(256,4), blk, 0, stream>>>(wq,wk,wv,wo, part);
  scale_final  <<<dim3(4),     blk, 0, stream>>>(part, scales);
  dequant_w    <<<dim3(WELEMS/(256*8),4), blk, 0, stream>>>(wq,wk,wv,wo, scales, Wh);
  cast_f16     <<<dim3((M2_*H_)/(256*8)), blk, 0, stream>>>(hs, Xh);

  // Q = X @ Wq^T ; K = X @ Wk^T   (M=8192, N=2048, K=2048)
  gemm8<0><<<dim3(8,32,1), gblk, 131072, stream>>>(Xh, Wh,        Qh, H_, H_, 1.f, 0,0,0);
  gemm8<0><<<dim3(8,32,1), gblk, 131072, stream>>>(Xh, Wh+WELEMS, Kh, H_, H_, 1.f, 0,0,0);

  rope_qk<<<dim3((B_*S_*16*64)/256), blk, 0, stream>>>(Qh, Kh, cosb, sinb);

  // scores = (Q @ K^T)/sqrt(hd), fp16, per batch: M=N=4096, K=2048
  gemm8<0><<<dim3(16,16,2), gblk, 131072, stream>>>(Qh, Kh, P, H_, S_, qksc,
      (long long)QOFF, (long long)QOFF, (long long)S_*S_);

  softmax_h<<<dim3(B_*S_), blk, 0, stream>>>(P, mask);

  // Vt = (X_b @ Wv^T)^T -> [b][h][tok] into Kh (dead): M=4096, N=2048, K=2048
  gemm8<1><<<dim3(8,16,2), gblk, 131072, stream>>>(Xh, Wh+2*WELEMS, Vt, H_, S_, 1.f,
      (long long)QOFF, 0, (long long)H_*S_);

  // AO_b = probs @ V = P[q,k]*Vt[h,k] -> Qh (dead): M=4096, N=2048, K=4096
  gemm8<0><<<dim3(8,16,2), gblk, 131072, stream>>>(P, Vt, AO, S_, H_, 1.f,
      (long long)S_*S_, (long long)H_*S_, (long long)QOFF);

  // out = AO @ Wo^T (fp32): M=8192, N=2048, K=2048
  gemm8<2><<<dim3(8,32,1), gblk, 131072, stream>>>(AO, Wh+3*WELEMS, d_out, H_, H_, 1.f, 0,0,0);
}

// Round 5
// 595.559 us; speedup vs baseline: 1.6894x; 1.0110x over previous
//
#include <hip/hip_runtime.h>
#include <hip/hip_bf16.h>
#include <stdint.h>

typedef _Float16 f16x8 __attribute__((ext_vector_type(8)));
typedef float f32x4 __attribute__((ext_vector_type(4)));
typedef unsigned short u16;

#define B_   2
#define S_   4096
#define H_   2048
#define M2_  8192              // B*S
#define WELEMS (H_*H_)         // 4194304 per weight

__device__ __forceinline__ u16 f2h(float f) {
  _Float16 h = (_Float16)f;                 // v_cvt_f16_f32, RNE
  return __builtin_bit_cast(unsigned short, h);
}
__device__ __forceinline__ float h2f(u16 b) {
  _Float16 h = __builtin_bit_cast(_Float16, b);
  return (float)h;
}

// async global->LDS, 16B per lane; dest = wave-uniform base + lane*16
__device__ __forceinline__ void gload16(const void* gptr, const void* lptr) {
  __builtin_amdgcn_global_load_lds(
      (const __attribute__((address_space(1))) void*)(uintptr_t)gptr,
      (__attribute__((address_space(3))) void*)(uint32_t)(uintptr_t)lptr,
      16, 0, 0);
}

// ---------------------------------------------------------------------------
// 256x256-tile BT GEMM, fp16 MFMA: C[m][n] = sum_k A[m][k]*B[n][k].
// BK=32, ring-4 LDS buffers (128 KiB), prefetch distance 2, counted vmcnt(4).
// Per tile: all 12 ds_read_b128 issued up front (order pinned), lgkmcnt(4)
// covers cluster-0 operands; cluster-1's reads (a4..a7) complete in the
// shadow of cluster 0's 16 MFMAs -> no exposed LDS stall for half 2.
// XOR-swizzled LDS via pre-swizzled global source (linear gload_lds dest).
// 512 threads = 8 waves (2M x 4N), per-wave 128x64 out, acc f32x4[8][4].
// EPI: 0 = fp16 C[m][n]*cs; 1 = fp16 transposed C[n][m]*cs; 2 = fp32*cs.
// ---------------------------------------------------------------------------
template<int EPI>
__global__ __launch_bounds__(512, 2)
void gemm8(const u16* __restrict__ A, const u16* __restrict__ B,
           void* __restrict__ Cv, int K, int ldc, float cscale,
           long long sA, long long sB, long long sC)
{
  extern __shared__ char smem[];            // 131072 B: A [0,64K), B [64K,128K)
  const int tid  = threadIdx.x;
  const int lane = tid & 63;
  const int wid  = tid >> 6;
  const int wm   = wid >> 2;                // 0..1
  const int wn   = wid & 3;                 // 0..3

  // XCD-bijective swizzle of flat block id within z-slice (nwg % 8 == 0)
  const int gx  = gridDim.x;
  const int nwg = gx * gridDim.y;
  int f = blockIdx.y * gx + blockIdx.x;
  f = (f & 7) * (nwg >> 3) + (f >> 3);
  const int brow = (f / gx) << 8;
  const int bcol = (f % gx) << 8;
  const int z    = blockIdx.z;

  const u16* Ab = A + (size_t)z * sA;
  const u16* Bb = B + (size_t)z * sB;

  // staging: thread t supplies LDS-linear bytes t*16; global src pre-swizzled:
  // row = 2*(t>>3) + ((t>>2)&1)  (+128 per 2nd issue), k8 = (t&3) ^ ((t>>3)&3)
  const int srow = ((tid >> 3) << 1) | ((tid >> 2) & 1);
  const int sk8  = (tid & 3) ^ ((tid >> 3) & 3);
  const u16* gA0 = Ab + (size_t)(brow + srow) * K + sk8 * 8;
  const u16* gA1 = gA0 + (size_t)128 * K;
  const u16* gB0 = Bb + (size_t)(bcol + srow) * K + sk8 * 8;
  const u16* gB1 = gB0 + (size_t)128 * K;

  char* ldsAw = smem + tid * 16;            // linear write dest (A region)
  char* ldsBw = ldsAw + 65536;              // B region

  // read side: byte(r,k8) = (r>>1)*128 + ((k8 ^ ((r>>1)&3))<<4) + ((r&1)<<6)
  const int l15 = lane & 15;
  const int lanepart = ((l15 >> 1) << 7) |
                       ((((lane >> 4) ^ ((l15 >> 1) & 3))) << 4) |
                       ((lane & 1) << 6);
  const char* ldsA = smem + (wm << 13) + lanepart;           // + wm*8192
  const char* ldsB = smem + 65536 + (wn << 12) + lanepart;   // + wn*4096

  f32x4 acc[8][4];
  #pragma unroll
  for (int i = 0; i < 8; ++i)
    #pragma unroll
    for (int j = 0; j < 4; ++j) acc[i][j] = (f32x4){0.f, 0.f, 0.f, 0.f};

#define DS_A(BUF, MH, MR) (*(const f16x8*)(ldsA + (BUF)*16384 + (MH)*4096 + (MR)*1024))
#define DS_B(BUF, NR)     (*(const f16x8*)(ldsB + (BUF)*16384 + (NR)*1024))

#define MFMA4(AM, AV) \
  acc[AM][0] = __builtin_amdgcn_mfma_f32_16x16x32_f16(AV, b0, acc[AM][0], 0, 0, 0); \
  acc[AM][1] = __builtin_amdgcn_mfma_f32_16x16x32_f16(AV, b1, acc[AM][1], 0, 0, 0); \
  acc[AM][2] = __builtin_amdgcn_mfma_f32_16x16x32_f16(AV, b2, acc[AM][2], 0, 0, 0); \
  acc[AM][3] = __builtin_amdgcn_mfma_f32_16x16x32_f16(AV, b3, acc[AM][3], 0, 0, 0);

#define TILE(BUF, IBUF, DOISS, LASTT) do {                                    \
    if (LASTT) { asm volatile("s_waitcnt vmcnt(0)" ::: "memory"); }           \
    else       { asm volatile("s_waitcnt vmcnt(4)" ::: "memory"); }           \
    __builtin_amdgcn_s_barrier();                                             \
    if (DOISS) {                                                              \
      gload16(gA0, ldsAw + (IBUF)*16384);                                     \
      gload16(gA1, ldsAw + (IBUF)*16384 + 8192);                              \
    }                                                                         \
    /* cluster-0 operands: 8 ds_read_b128 */                                  \
    f16x8 b0 = DS_B(BUF,0), b1 = DS_B(BUF,1), b2 = DS_B(BUF,2), b3 = DS_B(BUF,3); \
    f16x8 a0 = DS_A(BUF,0,0), a1 = DS_A(BUF,0,1), a2 = DS_A(BUF,0,2), a3 = DS_A(BUF,0,3); \
    __builtin_amdgcn_sched_barrier(0);   /* pin: first 8 issued before next 4 */ \
    /* cluster-1 operands: 4 ds_read_b128, complete under cluster-0 MFMA */   \
    f16x8 a4 = DS_A(BUF,1,0), a5 = DS_A(BUF,1,1), a6 = DS_A(BUF,1,2), a7 = DS_A(BUF,1,3); \
    asm volatile("s_waitcnt lgkmcnt(4)" ::: "memory");                        \
    __builtin_amdgcn_sched_barrier(0);                                        \
    __builtin_amdgcn_s_setprio(1);                                            \
    MFMA4(0, a0) MFMA4(1, a1) MFMA4(2, a2) MFMA4(3, a3)                       \
    __builtin_amdgcn_s_setprio(0);                                            \
    if (DOISS) {                                                              \
      gload16(gB0, ldsBw + (IBUF)*16384);                                     \
      gload16(gB1, ldsBw + (IBUF)*16384 + 8192);                              \
      gA0 += 32; gA1 += 32; gB0 += 32; gB1 += 32;                             \
    }                                                                         \
    asm volatile("s_waitcnt lgkmcnt(0)" ::: "memory");                        \
    __builtin_amdgcn_sched_barrier(0);                                        \
    __builtin_amdgcn_s_barrier();                                             \
    __builtin_amdgcn_s_setprio(1);                                            \
    MFMA4(4, a4) MFMA4(5, a5) MFMA4(6, a6) MFMA4(7, a7)                       \
    __builtin_amdgcn_s_setprio(0);                                            \
  } while (0)

  // prologue: stage tiles 0 and 1 (issue order per tile: A,A,B,B)
  gload16(gA0, ldsAw);          gload16(gA1, ldsAw + 8192);
  gload16(gB0, ldsBw);          gload16(gB1, ldsBw + 8192);
  gA0 += 32; gA1 += 32; gB0 += 32; gB1 += 32;
  gload16(gA0, ldsAw + 16384);  gload16(gA1, ldsAw + 16384 + 8192);
  gload16(gB0, ldsBw + 16384);  gload16(gB1, ldsBw + 16384 + 8192);
  gA0 += 32; gA1 += 32; gB0 += 32; gB1 += 32;

  const int NT4 = K >> 7;                   // (K/32)/4, K multiple of 128
  for (int it = 0; it < NT4; ++it) {
    const bool lst = (it == NT4 - 1);
    TILE(0, 2, true,  false);
    TILE(1, 3, true,  false);
    TILE(2, 0, !lst,  false);
    TILE(3, 1, !lst,  lst);
  }

#undef TILE
#undef MFMA4
#undef DS_A
#undef DS_B

  // C/D layout: col = lane&15, row = (lane>>4)*4 + reg
  const float scv = cscale;
  const int cr0 = brow + (wm << 7) + ((lane >> 4) << 2);
  const int cc0 = bcol + (wn << 6) + l15;

  if constexpr (EPI == 0) {                 // fp16 store
    u16* C = (u16*)Cv + (size_t)z * sC;
    #pragma unroll
    for (int am = 0; am < 8; ++am) {
      const int r = cr0 + am * 16;
      #pragma unroll
      for (int an = 0; an < 4; ++an) {
        const int c = cc0 + an * 16;
        #pragma unroll
        for (int j = 0; j < 4; ++j)
          C[(size_t)(r + j) * ldc + c] = f2h(acc[am][an][j] * scv);
      }
    }
  } else if constexpr (EPI == 1) {          // fp16 transposed store C[n][m]
    u16* C = (u16*)Cv + (size_t)z * sC;
    #pragma unroll
    for (int am = 0; am < 8; ++am) {
      const int r = cr0 + am * 16;
      #pragma unroll
      for (int an = 0; an < 4; ++an) {
        const int c = cc0 + an * 16;
        ushort4 pk;
        pk.x = f2h(acc[am][an][0] * scv);
        pk.y = f2h(acc[am][an][1] * scv);
        pk.z = f2h(acc[am][an][2] * scv);
        pk.w = f2h(acc[am][an][3] * scv);
        *(ushort4*)&C[(size_t)c * ldc + r] = pk;
      }
    }
  } else {                                  // fp32 store
    float* C = (float*)Cv + (size_t)z * sC;
    #pragma unroll
    for (int am = 0; am < 8; ++am) {
      const int r = cr0 + am * 16;
      #pragma unroll
      for (int an = 0; an < 4; ++an) {
        const int c = cc0 + an * 16;
        #pragma unroll
        for (int j = 0; j < 4; ++j)
          C[(size_t)(r + j) * ldc + c] = acc[am][an][j] * scv;
      }
    }
  }
}

// ---------------------------------------------------------------------------
// bitlinear scale: two-stage deterministic mean(|w|)
// ---------------------------------------------------------------------------
__global__ __launch_bounds__(256)
void abssum_partial(const float* __restrict__ w0, const float* __restrict__ w1,
                    const float* __restrict__ w2, const float* __restrict__ w3,
                    float* __restrict__ part)
{
  const float* w = (blockIdx.y==0)?w0:(blockIdx.y==1)?w1:(blockIdx.y==2)?w2:w3;
  float s = 0.f;
  const int N4 = WELEMS/4;
  for (int i = blockIdx.x*256 + threadIdx.x; i < N4; i += 256*256) {
    float4 v = ((const float4*)w)[i];
    s += fabsf(v.x)+fabsf(v.y)+fabsf(v.z)+fabsf(v.w);
  }
  #pragma unroll
  for (int o=32;o;o>>=1) s += __shfl_xor(s,o);
  __shared__ float r[4];
  if ((threadIdx.x&63)==0) r[threadIdx.x>>6] = s;
  __syncthreads();
  if (threadIdx.x==0) part[blockIdx.y*256 + blockIdx.x] = (r[0]+r[1])+(r[2]+r[3]);
}

__global__ __launch_bounds__(256)
void scale_final(const float* __restrict__ part, float* __restrict__ scales)
{
  float s = part[blockIdx.x*256 + threadIdx.x];
  #pragma unroll
  for (int o=32;o;o>>=1) s += __shfl_xor(s,o);
  __shared__ float r[4];
  if ((threadIdx.x&63)==0) r[threadIdx.x>>6] = s;
  __syncthreads();
  if (threadIdx.x==0) scales[blockIdx.x] = ((r[0]+r[1])+(r[2]+r[3])) * (1.f/(float)WELEMS);
}

// ternary quant + fp16 dequant: w -> rint(clip(w/(s+eps)))*s, stored fp16
__global__ __launch_bounds__(256)
void dequant_w(const float* __restrict__ w0, const float* __restrict__ w1,
               const float* __restrict__ w2, const float* __restrict__ w3,
               const float* __restrict__ scales, u16* __restrict__ out)
{
  const int wi = blockIdx.y;
  const float* w = (wi==0)?w0:(wi==1)?w1:(wi==2)?w2:w3;
  u16* o = out + (size_t)wi * WELEMS;
  const float scv = scales[wi];
  const float inv = 1.f/(scv + 1e-5f);
  const int i0 = (blockIdx.x*256 + threadIdx.x)*8;
  float4 a = *(const float4*)(w + i0);
  float4 b = *(const float4*)(w + i0 + 4);
  float t[8] = {a.x,a.y,a.z,a.w,b.x,b.y,b.z,b.w};
  union { uint4 v; u16 h[8]; } r;
  #pragma unroll
  for (int j=0;j<8;++j){
    float x = t[j]*inv;
    x = fminf(fmaxf(x,-1.f),1.f);
    r.h[j] = f2h(rintf(x)*scv);
  }
  *(uint4*)(o + i0) = r.v;
}

__global__ __launch_bounds__(256)
void cast_f16(const float* __restrict__ x, u16* __restrict__ o)
{
  const int i0 = (blockIdx.x*256 + threadIdx.x)*8;
  float4 a = *(const float4*)(x + i0);
  float4 b = *(const float4*)(x + i0 + 4);
  float t[8] = {a.x,a.y,a.z,a.w,b.x,b.y,b.z,b.w};
  union { uint4 v; u16 h[8]; } r;
  #pragma unroll
  for (int j=0;j<8;++j) r.h[j] = f2h(t[j]);
  *(uint4*)(o + i0) = r.v;
}

// in-place RoPE on fp16 Q and K (pair d, d+64 within each 128-dim chunk)
__global__ __launch_bounds__(256)
void rope_qk(u16* __restrict__ Q, u16* __restrict__ K,
             const float* __restrict__ cosb, const float* __restrict__ sinb)
{
  const uint32_t idx = blockIdx.x*256 + threadIdx.x;   // < 2*4096*16*64
  const int d   = idx & 63;
  const int h16 = (idx >> 6) & 15;
  const int s   = (idx >> 10) & (S_-1);
  const int b   = idx >> 22;
  const size_t base = ((size_t)b*S_ + s)*H_ + h16*128 + d;
  const int ci = s*128 + d;
  const float c0 = cosb[ci], c1 = cosb[ci+64];
  const float s0 = sinb[ci], s1 = sinb[ci+64];
  const float q0 = h2f(Q[base]), q1 = h2f(Q[base+64]);
  Q[base]    = f2h(q0*c0 - q1*s0);
  Q[base+64] = f2h(q1*c1 + q0*s1);
  const float k0 = h2f(K[base]), k1 = h2f(K[base+64]);
  K[base]    = f2h(k0*c0 - k1*s0);
  K[base+64] = f2h(k1*c1 + k0*s1);
}

// row softmax over S_=4096, in place on fp16 scores (scale already applied);
// adds mask, writes fp16 probs
__global__ __launch_bounds__(256)
void softmax_h(u16* __restrict__ P, const float* __restrict__ mask)
{
  const int row = blockIdx.x;               // 0..B_*S_-1
  const int q   = row & (S_-1);
  u16* prow = P + (size_t)row * S_;
  const float* mrow = mask + (size_t)q * S_;
  const int tid  = threadIdx.x;
  const int lane = tid & 63;
  const int base = tid * 16;

  union { uint4 v[2]; u16 h[16]; } sv;
  sv.v[0] = *(const uint4*)(prow + base);
  sv.v[1] = *(const uint4*)(prow + base + 8);
  float mk[16];
  #pragma unroll
  for (int j=0;j<4;++j) ((float4*)mk)[j] = *(const float4*)(mrow + base + 4*j);

  float v[16];
  #pragma unroll
  for (int i=0;i<16;++i) v[i] = h2f(sv.h[i]) + mk[i];

  float mx = v[0];
  #pragma unroll
  for (int i=1;i<16;++i) mx = fmaxf(mx, v[i]);
  #pragma unroll
  for (int o=32;o;o>>=1) mx = fmaxf(mx, __shfl_xor(mx, o));
  __shared__ float red[8];
  if (lane==0) red[tid>>6] = mx;
  __syncthreads();
  mx = fmaxf(fmaxf(red[0],red[1]), fmaxf(red[2],red[3]));

  float e[16]; float sm = 0.f;
  #pragma unroll
  for (int i=0;i<16;++i){ e[i] = __expf(v[i]-mx); sm += e[i]; }
  #pragma unroll
  for (int o=32;o;o>>=1) sm += __shfl_xor(sm, o);
  if (lane==0) red[4 + (tid>>6)] = sm;
  __syncthreads();
  sm = (red[4]+red[5])+(red[6]+red[7]);
  const float inv = 1.f/sm;

  union { uint4 v[2]; u16 h[16]; } ov;
  #pragma unroll
  for (int i=0;i<16;++i) ov.h[i] = f2h(e[i]*inv);
  *(uint4*)(prow + base)     = ov.v[0];
  *(uint4*)(prow + base + 8) = ov.v[1];
}

__global__ void fill_f32(float* p, float v, int n) {
  int i = blockIdx.x*256 + threadIdx.x;
  if (i < n) p[i] = v;
}

// ---------------------------------------------------------------------------
extern "C" void kernel_launch(void* const* d_in, const int* in_sizes, int n_in,
                              void* d_out, int out_size, void* d_ws, size_t ws_size,
                              hipStream_t stream)
{
  const float* hs   = (const float*)d_in[0];
  const float* mask = (const float*)d_in[1];
  const float* cosb = (const float*)d_in[2];
  const float* sinb = (const float*)d_in[3];
  const float* wq   = (const float*)d_in[4];
  const float* wk   = (const float*)d_in[5];
  const float* wv   = (const float*)d_in[6];
  const float* wo   = (const float*)d_in[7];

  // ws layout, 128 MiB exactly (lifetime aliasing):
  //   Wh [0,32M)   : 4 pre-scaled ternary weights, fp16    (live whole call)
  //   Xh [32,64M)  : hidden_states fp16                    (dead after Vt)
  //   Qh [64,96M)  : Q fp16 -> AO (PV output) per batch
  //   Kh [96,128M) : K fp16 -> Vt[b][h][tok] per batch
  // d_out: part/scales (head, pre-GEMM) -> fp16 scores/probs both batches
  //        (64 MiB exactly) -> final fp32 output.
  char* w = (char*)d_ws;
  const size_t SZ = (size_t)M2_ * H_ * 2;   // 32 MiB
  u16* Wh = (u16*)(w);
  u16* Xh = (u16*)(w + SZ);
  u16* Qh = (u16*)(w + 2*SZ);
  u16* Kh = (u16*)(w + 3*SZ);
  u16* AO = Qh;                              // alias after QK^T
  u16* Vt = Kh;                              // alias after QK^T
  float* part   = (float*)d_out;             // dead before scores written
  float* scales = part + 1024;
  u16* P  = (u16*)d_out;                     // fp16 scores/probs, both batches

  const size_t need = 4*SZ;                  // 134,217,728 B
  if (ws_size < need || out_size != M2_*H_) {
    float v = (out_size != M2_*H_) ? 2.0e9f : (float)ws_size;
    fill_f32<<<dim3((out_size+255)/256), dim3(256), 0, stream>>>((float*)d_out, v, out_size);
    return;
  }

  dim3 blk(256), gblk(512);
  const size_t QOFF = (size_t)S_*H_;         // per-batch elems
  const float qksc = 0.08838834764831845f;   // 1/sqrt(128)

  abssum_partial<<<dim3(256,4), blk, 0, stream>>>(wq,wk,wv,wo, part);
  scale_final  <<<dim3(4),     blk, 0, stream>>>(part, scales);
  dequant_w    <<<dim3(WELEMS/(256*8),4), blk, 0, stream>>>(wq,wk,wv,wo, scales, Wh);
  cast_f16     <<<dim3((M2_*H_)/(256*8)), blk, 0, stream>>>(hs, Xh);

  // Q = X @ Wq^T ; K = X @ Wk^T   (M=8192, N=2048, K=2048)
  gemm8<0><<<dim3(8,32,1), gblk, 131072, stream>>>(Xh, Wh,        Qh, H_, H_, 1.f, 0,0,0);
  gemm8<0><<<dim3(8,32,1), gblk, 131072, stream>>>(Xh, Wh+WELEMS, Kh, H_, H_, 1.f, 0,0,0);

  rope_qk<<<dim3((B_*S_*16*64)/256), blk, 0, stream>>>(Qh, Kh, cosb, sinb);

  // scores = (Q @ K^T)/sqrt(hd), fp16, per batch: M=N=4096, K=2048
  gemm8<0><<<dim3(16,16,2), gblk, 131072, stream>>>(Qh, Kh, P, H_, S_, qksc,
      (long long)QOFF, (long long)QOFF, (long long)S_*S_);

  softmax_h<<<dim3(B_*S_), blk, 0, stream>>>(P, mask);

  // Vt = (X_b @ Wv^T)^T -> [b][h][tok] into Kh (dead): M=4096, N=2048, K=2048
  gemm8<1><<<dim3(8,16,2), gblk, 131072, stream>>>(Xh, Wh+2*WELEMS, Vt, H_, S_, 1.f,
      (long long)QOFF, 0, (long long)H_*S_);

  // AO_b = probs @ V = P[q,k]*Vt[h,k] -> Qh (dead): M=4096, N=2048, K=4096
  gemm8<0><<<dim3(8,16,2), gblk, 131072, stream>>>(P, Vt, AO, S_, H_, 1.f,
      (long long)S_*S_, (long long)H_*S_, (long long)QOFF);

  // out = AO @ Wo^T (fp32): M=8192, N=2048, K=2048
  gemm8<2><<<dim3(8,32,1), gblk, 131072, stream>>>(AO, Wh+3*WELEMS, d_out, H_, H_, 1.f, 0,0,0);
}

// Round 6
// 595.300 us; speedup vs baseline: 1.6901x; 1.0004x over previous
//
#include <hip/hip_runtime.h>
#include <hip/hip_bf16.h>
#include <stdint.h>

typedef _Float16 f16x8 __attribute__((ext_vector_type(8)));
typedef float f32x4 __attribute__((ext_vector_type(4)));
typedef unsigned short u16;

#define B_   2
#define S_   4096
#define H_   2048
#define M2_  8192              // B*S
#define WELEMS (H_*H_)         // 4194304 per weight

__device__ __forceinline__ u16 f2h(float f) {
  _Float16 h = (_Float16)f;                 // v_cvt_f16_f32, RNE
  return __builtin_bit_cast(unsigned short, h);
}
__device__ __forceinline__ float h2f(u16 b) {
  _Float16 h = __builtin_bit_cast(_Float16, b);
  return (float)h;
}

// async global->LDS, 16B per lane; dest = wave-uniform base + lane*16
__device__ __forceinline__ void gload16(const void* gptr, const void* lptr) {
  __builtin_amdgcn_global_load_lds(
      (const __attribute__((address_space(1))) void*)(uintptr_t)gptr,
      (__attribute__((address_space(3))) void*)(uint32_t)(uintptr_t)lptr,
      16, 0, 0);
}

// ---------------------------------------------------------------------------
// 256x256-tile BT GEMM, fp16 MFMA: C[m][n] = sum_k A[m][k]*B[n][k].
// BK=32, ring-4 LDS buffers (128 KiB), prefetch distance 2, counted vmcnt(4).
// Per tile: all 12 ds_read_b128 issued up front (order pinned), lgkmcnt(4)
// covers cluster-0 operands; cluster-1's reads (a4..a7) complete in the
// shadow of cluster 0's 16 MFMAs -> no exposed LDS stall for half 2.
// XOR-swizzled LDS via pre-swizzled global source (linear gload_lds dest).
// 512 threads = 8 waves (2M x 4N), per-wave 128x64 out, acc f32x4[8][4].
// EPI: 0 = fp16 C[m][n]*cs; 1 = fp16 transposed C[n][m]*cs; 2 = fp32*cs.
// ---------------------------------------------------------------------------
template<int EPI>
__global__ __launch_bounds__(512, 2)
void gemm8(const u16* __restrict__ A, const u16* __restrict__ B,
           void* __restrict__ Cv, int K, int ldc, float cscale,
           long long sA, long long sB, long long sC)
{
  extern __shared__ char smem[];            // 131072 B: A [0,64K), B [64K,128K)
  const int tid  = threadIdx.x;
  const int lane = tid & 63;
  const int wid  = tid >> 6;
  const int wm   = wid >> 2;                // 0..1
  const int wn   = wid & 3;                 // 0..3

  // XCD-bijective swizzle of flat block id within z-slice (nwg % 8 == 0)
  const int gx  = gridDim.x;
  const int nwg = gx * gridDim.y;
  int f = blockIdx.y * gx + blockIdx.x;
  f = (f & 7) * (nwg >> 3) + (f >> 3);
  const int brow = (f / gx) << 8;
  const int bcol = (f % gx) << 8;
  const int z    = blockIdx.z;

  const u16* Ab = A + (size_t)z * sA;
  const u16* Bb = B + (size_t)z * sB;

  // staging: thread t supplies LDS-linear bytes t*16; global src pre-swizzled:
  // row = 2*(t>>3) + ((t>>2)&1)  (+128 per 2nd issue), k8 = (t&3) ^ ((t>>3)&3)
  const int srow = ((tid >> 3) << 1) | ((tid >> 2) & 1);
  const int sk8  = (tid & 3) ^ ((tid >> 3) & 3);
  const u16* gA0 = Ab + (size_t)(brow + srow) * K + sk8 * 8;
  const u16* gA1 = gA0 + (size_t)128 * K;
  const u16* gB0 = Bb + (size_t)(bcol + srow) * K + sk8 * 8;
  const u16* gB1 = gB0 + (size_t)128 * K;

  char* ldsAw = smem + tid * 16;            // linear write dest (A region)
  char* ldsBw = ldsAw + 65536;              // B region

  // read side: byte(r,k8) = (r>>1)*128 + ((k8 ^ ((r>>1)&3))<<4) + ((r&1)<<6)
  const int l15 = lane & 15;
  const int lanepart = ((l15 >> 1) << 7) |
                       ((((lane >> 4) ^ ((l15 >> 1) & 3))) << 4) |
                       ((lane & 1) << 6);
  const char* ldsA = smem + (wm << 13) + lanepart;           // + wm*8192
  const char* ldsB = smem + 65536 + (wn << 12) + lanepart;   // + wn*4096

  f32x4 acc[8][4];
  #pragma unroll
  for (int i = 0; i < 8; ++i)
    #pragma unroll
    for (int j = 0; j < 4; ++j) acc[i][j] = (f32x4){0.f, 0.f, 0.f, 0.f};

#define DS_A(BUF, MH, MR) (*(const f16x8*)(ldsA + (BUF)*16384 + (MH)*4096 + (MR)*1024))
#define DS_B(BUF, NR)     (*(const f16x8*)(ldsB + (BUF)*16384 + (NR)*1024))

#define MFMA4(AM, AV) \
  acc[AM][0] = __builtin_amdgcn_mfma_f32_16x16x32_f16(AV, b0, acc[AM][0], 0, 0, 0); \
  acc[AM][1] = __builtin_amdgcn_mfma_f32_16x16x32_f16(AV, b1, acc[AM][1], 0, 0, 0); \
  acc[AM][2] = __builtin_amdgcn_mfma_f32_16x16x32_f16(AV, b2, acc[AM][2], 0, 0, 0); \
  acc[AM][3] = __builtin_amdgcn_mfma_f32_16x16x32_f16(AV, b3, acc[AM][3], 0, 0, 0);

#define TILE(BUF, IBUF, DOISS, LASTT) do {                                    \
    if (LASTT) { asm volatile("s_waitcnt vmcnt(0)" ::: "memory"); }           \
    else       { asm volatile("s_waitcnt vmcnt(4)" ::: "memory"); }           \
    __builtin_amdgcn_s_barrier();                                             \
    if (DOISS) {                                                              \
      gload16(gA0, ldsAw + (IBUF)*16384);                                     \
      gload16(gA1, ldsAw + (IBUF)*16384 + 8192);                              \
    }                                                                         \
    /* cluster-0 operands: 8 ds_read_b128 */                                  \
    f16x8 b0 = DS_B(BUF,0), b1 = DS_B(BUF,1), b2 = DS_B(BUF,2), b3 = DS_B(BUF,3); \
    f16x8 a0 = DS_A(BUF,0,0), a1 = DS_A(BUF,0,1), a2 = DS_A(BUF,0,2), a3 = DS_A(BUF,0,3); \
    __builtin_amdgcn_sched_barrier(0);   /* pin: first 8 issued before next 4 */ \
    /* cluster-1 operands: 4 ds_read_b128, complete under cluster-0 MFMA */   \
    f16x8 a4 = DS_A(BUF,1,0), a5 = DS_A(BUF,1,1), a6 = DS_A(BUF,1,2), a7 = DS_A(BUF,1,3); \
    asm volatile("s_waitcnt lgkmcnt(4)" ::: "memory");                        \
    __builtin_amdgcn_sched_barrier(0);                                        \
    __builtin_amdgcn_s_setprio(1);                                            \
    MFMA4(0, a0) MFMA4(1, a1) MFMA4(2, a2) MFMA4(3, a3)                       \
    __builtin_amdgcn_s_setprio(0);                                            \
    if (DOISS) {                                                              \
      gload16(gB0, ldsBw + (IBUF)*16384);                                     \
      gload16(gB1, ldsBw + (IBUF)*16384 + 8192);                              \
      gA0 += 32; gA1 += 32; gB0 += 32; gB1 += 32;                             \
    }                                                                         \
    asm volatile("s_waitcnt lgkmcnt(0)" ::: "memory");                        \
    __builtin_amdgcn_sched_barrier(0);                                        \
    __builtin_amdgcn_s_barrier();                                             \
    __builtin_amdgcn_s_setprio(1);                                            \
    MFMA4(4, a4) MFMA4(5, a5) MFMA4(6, a6) MFMA4(7, a7)                       \
    __builtin_amdgcn_s_setprio(0);                                            \
  } while (0)

  // prologue: stage tiles 0 and 1 (issue order per tile: A,A,B,B)
  gload16(gA0, ldsAw);          gload16(gA1, ldsAw + 8192);
  gload16(gB0, ldsBw);          gload16(gB1, ldsBw + 8192);
  gA0 += 32; gA1 += 32; gB0 += 32; gB1 += 32;
  gload16(gA0, ldsAw + 16384);  gload16(gA1, ldsAw + 16384 + 8192);
  gload16(gB0, ldsBw + 16384);  gload16(gB1, ldsBw + 16384 + 8192);
  gA0 += 32; gA1 += 32; gB0 += 32; gB1 += 32;

  const int NT4 = K >> 7;                   // (K/32)/4, K multiple of 128
  for (int it = 0; it < NT4; ++it) {
    const bool lst = (it == NT4 - 1);
    TILE(0, 2, true,  false);
    TILE(1, 3, true,  false);
    TILE(2, 0, !lst,  false);
    TILE(3, 1, !lst,  lst);
  }

#undef TILE
#undef MFMA4
#undef DS_A
#undef DS_B

  // C/D layout: col = lane&15, row = (lane>>4)*4 + reg
  const float scv = cscale;
  const int cr0 = brow + (wm << 7) + ((lane >> 4) << 2);
  const int cc0 = bcol + (wn << 6) + l15;

  if constexpr (EPI == 0) {                 // fp16 store
    u16* C = (u16*)Cv + (size_t)z * sC;
    #pragma unroll
    for (int am = 0; am < 8; ++am) {
      const int r = cr0 + am * 16;
      #pragma unroll
      for (int an = 0; an < 4; ++an) {
        const int c = cc0 + an * 16;
        #pragma unroll
        for (int j = 0; j < 4; ++j)
          C[(size_t)(r + j) * ldc + c] = f2h(acc[am][an][j] * scv);
      }
    }
  } else if constexpr (EPI == 1) {          // fp16 transposed store C[n][m]
    u16* C = (u16*)Cv + (size_t)z * sC;
    #pragma unroll
    for (int am = 0; am < 8; ++am) {
      const int r = cr0 + am * 16;
      #pragma unroll
      for (int an = 0; an < 4; ++an) {
        const int c = cc0 + an * 16;
        ushort4 pk;
        pk.x = f2h(acc[am][an][0] * scv);
        pk.y = f2h(acc[am][an][1] * scv);
        pk.z = f2h(acc[am][an][2] * scv);
        pk.w = f2h(acc[am][an][3] * scv);
        *(ushort4*)&C[(size_t)c * ldc + r] = pk;
      }
    }
  } else {                                  // fp32 store
    float* C = (float*)Cv + (size_t)z * sC;
    #pragma unroll
    for (int am = 0; am < 8; ++am) {
      const int r = cr0 + am * 16;
      #pragma unroll
      for (int an = 0; an < 4; ++an) {
        const int c = cc0 + an * 16;
        #pragma unroll
        for (int j = 0; j < 4; ++j)
          C[(size_t)(r + j) * ldc + c] = acc[am][an][j] * scv;
      }
    }
  }
}

// ---------------------------------------------------------------------------
// bitlinear scale: two-stage deterministic mean(|w|)
// ---------------------------------------------------------------------------
__global__ __launch_bounds__(256)
void abssum_partial(const float* __restrict__ w0, const float* __restrict__ w1,
                    const float* __restrict__ w2, const float* __restrict__ w3,
                    float* __restrict__ part)
{
  const float* w = (blockIdx.y==0)?w0:(blockIdx.y==1)?w1:(blockIdx.y==2)?w2:w3;
  float s = 0.f;
  const int N4 = WELEMS/4;
  for (int i = blockIdx.x*256 + threadIdx.x; i < N4; i += 256*256) {
    float4 v = ((const float4*)w)[i];
    s += fabsf(v.x)+fabsf(v.y)+fabsf(v.z)+fabsf(v.w);
  }
  #pragma unroll
  for (int o=32;o;o>>=1) s += __shfl_xor(s,o);
  __shared__ float r[4];
  if ((threadIdx.x&63)==0) r[threadIdx.x>>6] = s;
  __syncthreads();
  if (threadIdx.x==0) part[blockIdx.y*256 + blockIdx.x] = (r[0]+r[1])+(r[2]+r[3]);
}

__global__ __launch_bounds__(256)
void scale_final(const float* __restrict__ part, float* __restrict__ scales)
{
  float s = part[blockIdx.x*256 + threadIdx.x];
  #pragma unroll
  for (int o=32;o;o>>=1) s += __shfl_xor(s,o);
  __shared__ float r[4];
  if ((threadIdx.x&63)==0) r[threadIdx.x>>6] = s;
  __syncthreads();
  if (threadIdx.x==0) scales[blockIdx.x] = ((r[0]+r[1])+(r[2]+r[3])) * (1.f/(float)WELEMS);
}

// ternary quant + fp16 dequant: w -> rint(clip(w/(s+eps)))*s, stored fp16
__global__ __launch_bounds__(256)
void dequant_w(const float* __restrict__ w0, const float* __restrict__ w1,
               const float* __restrict__ w2, const float* __restrict__ w3,
               const float* __restrict__ scales, u16* __restrict__ out)
{
  const int wi = blockIdx.y;
  const float* w = (wi==0)?w0:(wi==1)?w1:(wi==2)?w2:w3;
  u16* o = out + (size_t)wi * WELEMS;
  const float scv = scales[wi];
  const float inv = 1.f/(scv + 1e-5f);
  const int i0 = (blockIdx.x*256 + threadIdx.x)*8;
  float4 a = *(const float4*)(w + i0);
  float4 b = *(const float4*)(w + i0 + 4);
  float t[8] = {a.x,a.y,a.z,a.w,b.x,b.y,b.z,b.w};
  union { uint4 v; u16 h[8]; } r;
  #pragma unroll
  for (int j=0;j<8;++j){
    float x = t[j]*inv;
    x = fminf(fmaxf(x,-1.f),1.f);
    r.h[j] = f2h(rintf(x)*scv);
  }
  *(uint4*)(o + i0) = r.v;
}

__global__ __launch_bounds__(256)
void cast_f16(const float* __restrict__ x, u16* __restrict__ o)
{
  const int i0 = (blockIdx.x*256 + threadIdx.x)*8;
  float4 a = *(const float4*)(x + i0);
  float4 b = *(const float4*)(x + i0 + 4);
  float t[8] = {a.x,a.y,a.z,a.w,b.x,b.y,b.z,b.w};
  union { uint4 v; u16 h[8]; } r;
  #pragma unroll
  for (int j=0;j<8;++j) r.h[j] = f2h(t[j]);
  *(uint4*)(o + i0) = r.v;
}

// in-place RoPE on fp16 Q and K (pair d, d+64 within each 128-dim chunk)
__global__ __launch_bounds__(256)
void rope_qk(u16* __restrict__ Q, u16* __restrict__ K,
             const float* __restrict__ cosb, const float* __restrict__ sinb)
{
  const uint32_t idx = blockIdx.x*256 + threadIdx.x;   // < 2*4096*16*64
  const int d   = idx & 63;
  const int h16 = (idx >> 6) & 15;
  const int s   = (idx >> 10) & (S_-1);
  const int b   = idx >> 22;
  const size_t base = ((size_t)b*S_ + s)*H_ + h16*128 + d;
  const int ci = s*128 + d;
  const float c0 = cosb[ci], c1 = cosb[ci+64];
  const float s0 = sinb[ci], s1 = sinb[ci+64];
  const float q0 = h2f(Q[base]), q1 = h2f(Q[base+64]);
  Q[base]    = f2h(q0*c0 - q1*s0);
  Q[base+64] = f2h(q1*c1 + q0*s1);
  const float k0 = h2f(K[base]), k1 = h2f(K[base+64]);
  K[base]    = f2h(k0*c0 - k1*s0);
  K[base+64] = f2h(k1*c1 + k0*s1);
}

// row softmax over S_=4096, in place on fp16 scores (scale already applied);
// adds mask, writes fp16 probs
__global__ __launch_bounds__(256)
void softmax_h(u16* __restrict__ P, const float* __restrict__ mask)
{
  const int row = blockIdx.x;               // 0..B_*S_-1
  const int q   = row & (S_-1);
  u16* prow = P + (size_t)row * S_;
  const float* mrow = mask + (size_t)q * S_;
  const int tid  = threadIdx.x;
  const int lane = tid & 63;
  const int base = tid * 16;

  union { uint4 v[2]; u16 h[16]; } sv;
  sv.v[0] = *(const uint4*)(prow + base);
  sv.v[1] = *(const uint4*)(prow + base + 8);
  float mk[16];
  #pragma unroll
  for (int j=0;j<4;++j) ((float4*)mk)[j] = *(const float4*)(mrow + base + 4*j);

  float v[16];
  #pragma unroll
  for (int i=0;i<16;++i) v[i] = h2f(sv.h[i]) + mk[i];

  float mx = v[0];
  #pragma unroll
  for (int i=1;i<16;++i) mx = fmaxf(mx, v[i]);
  #pragma unroll
  for (int o=32;o;o>>=1) mx = fmaxf(mx, __shfl_xor(mx, o));
  __shared__ float red[8];
  if (lane==0) red[tid>>6] = mx;
  __syncthreads();
  mx = fmaxf(fmaxf(red[0],red[1]), fmaxf(red[2],red[3]));

  float e[16]; float sm = 0.f;
  #pragma unroll
  for (int i=0;i<16;++i){ e[i] = __expf(v[i]-mx); sm += e[i]; }
  #pragma unroll
  for (int o=32;o;o>>=1) sm += __shfl_xor(sm, o);
  if (lane==0) red[4 + (tid>>6)] = sm;
  __syncthreads();
  sm = (red[4]+red[5])+(red[6]+red[7]);
  const float inv = 1.f/sm;

  union { uint4 v[2]; u16 h[16]; } ov;
  #pragma unroll
  for (int i=0;i<16;++i) ov.h[i] = f2h(e[i]*inv);
  *(uint4*)(prow + base)     = ov.v[0];
  *(uint4*)(prow + base + 8) = ov.v[1];
}

__global__ void fill_f32(float* p, float v, int n) {
  int i = blockIdx.x*256 + threadIdx.x;
  if (i < n) p[i] = v;
}

// ---------------------------------------------------------------------------
extern "C" void kernel_launch(void* const* d_in, const int* in_sizes, int n_in,
                              void* d_out, int out_size, void* d_ws, size_t ws_size,
                              hipStream_t stream)
{
  const float* hs   = (const float*)d_in[0];
  const float* mask = (const float*)d_in[1];
  const float* cosb = (const float*)d_in[2];
  const float* sinb = (const float*)d_in[3];
  const float* wq   = (const float*)d_in[4];
  const float* wk   = (const float*)d_in[5];
  const float* wv   = (const float*)d_in[6];
  const float* wo   = (const float*)d_in[7];

  // ws layout, 128 MiB exactly (lifetime aliasing):
  //   Wh [0,32M)   : 4 pre-scaled ternary weights, fp16    (live whole call)
  //   Xh [32,64M)  : hidden_states fp16                    (dead after Vt)
  //   Qh [64,96M)  : Q fp16 -> AO (PV output) per batch
  //   Kh [96,128M) : K fp16 -> Vt[b][h][tok] per batch
  // d_out: part/scales (head, pre-GEMM) -> fp16 scores/probs both batches
  //        (64 MiB exactly) -> final fp32 output.
  char* w = (char*)d_ws;
  const size_t SZ = (size_t)M2_ * H_ * 2;   // 32 MiB
  u16* Wh = (u16*)(w);
  u16* Xh = (u16*)(w + SZ);
  u16* Qh = (u16*)(w + 2*SZ);
  u16* Kh = (u16*)(w + 3*SZ);
  u16* AO = Qh;                              // alias after QK^T
  u16* Vt = Kh;                              // alias after QK^T
  float* part   = (float*)d_out;             // dead before scores written
  float* scales = part + 1024;
  u16* P  = (u16*)d_out;                     // fp16 scores/probs, both batches

  const size_t need = 4*SZ;                  // 134,217,728 B
  if (ws_size < need || out_size != M2_*H_) {
    float v = (out_size != M2_*H_) ? 2.0e9f : (float)ws_size;
    fill_f32<<<dim3((out_size+255)/256), dim3(256), 0, stream>>>((float*)d_out, v, out_size);
    return;
  }

  dim3 blk(256), gblk(512);
  const size_t QOFF = (size_t)S_*H_;         // per-batch elems
  const float qksc = 0.08838834764831845f;   // 1/sqrt(128)

  abssum_partial<<<dim3(256,4), blk, 0, stream>>>(wq,wk,wv,wo, part);
  scale_final  <<<dim3(4),     blk, 0, stream>>>(part, scales);
  dequant_w    <<<dim3(WELEMS/(256*8),4), blk, 0, stream>>>(wq,wk,wv,wo, scales, Wh);
  cast_f16     <<<dim3((M2_*H_)/(256*8)), blk, 0, stream>>>(hs, Xh);

  // Q = X @ Wq^T ; K = X @ Wk^T   (M=8192, N=2048, K=2048)
  gemm8<0><<<dim3(8,32,1), gblk, 131072, stream>>>(Xh, Wh,        Qh, H_, H_, 1.f, 0,0,0);
  gemm8<0><<<dim3(8,32,1), gblk, 131072, stream>>>(Xh, Wh+WELEMS, Kh, H_, H_, 1.f, 0,0,0);

  rope_qk<<<dim3((B_*S_*16*64)/256), blk, 0, stream>>>(Qh, Kh, cosb, sinb);

  // scores = (Q @ K^T)/sqrt(hd), fp16, per batch: M=N=4096, K=2048
  gemm8<0><<<dim3(16,16,2), gblk, 131072, stream>>>(Qh, Kh, P, H_, S_, qksc,
      (long long)QOFF, (long long)QOFF, (long long)S_*S_);

  softmax_h<<<dim3(B_*S_), blk, 0, stream>>>(P, mask);

  // Vt = (X_b @ Wv^T)^T -> [b][h][tok] into Kh (dead): M=4096, N=2048, K=2048
  gemm8<1><<<dim3(8,16,2), gblk, 131072, stream>>>(Xh, Wh+2*WELEMS, Vt, H_, S_, 1.f,
      (long long)QOFF, 0, (long long)H_*S_);

  // AO_b = probs @ V = P[q,k]*Vt[h,k] -> Qh (dead): M=4096, N=2048, K=4096
  gemm8<0><<<dim3(8,16,2), gblk, 131072, stream>>>(P, Vt, AO, S_, H_, 1.f,
      (long long)S_*S_, (long long)H_*S_, (long long)QOFF);

  // out = AO @ Wo^T (fp32): M=8192, N=2048, K=2048
  gemm8<2><<<dim3(8,32,1), gblk, 131072, stream>>>(AO, Wh+3*WELEMS, d_out, H_, H_, 1.f, 0,0,0);
}

// Round 7
// 594.794 us; speedup vs baseline: 1.6916x; 1.0009x over previous
//
#include <hip/hip_runtime.h>
#include <hip/hip_bf16.h>
#include <stdint.h>

typedef _Float16 f16x8 __attribute__((ext_vector_type(8)));
typedef float f32x4 __attribute__((ext_vector_type(4)));
typedef unsigned short u16;

#define B_   2
#define S_   4096
#define H_   2048
#define M2_  8192              // B*S
#define WELEMS (H_*H_)         // 4194304 per weight

__device__ __forceinline__ u16 f2h(float f) {
  _Float16 h = (_Float16)f;                 // v_cvt_f16_f32, RNE
  return __builtin_bit_cast(unsigned short, h);
}
__device__ __forceinline__ float h2f(u16 b) {
  _Float16 h = __builtin_bit_cast(_Float16, b);
  return (float)h;
}

// async global->LDS, 16B per lane; dest = wave-uniform base + lane*16
__device__ __forceinline__ void gload16(const void* gptr, const void* lptr) {
  __builtin_amdgcn_global_load_lds(
      (const __attribute__((address_space(1))) void*)(uintptr_t)gptr,
      (__attribute__((address_space(3))) void*)(uint32_t)(uintptr_t)lptr,
      16, 0, 0);
}

// ---------------------------------------------------------------------------
// 256x256-tile BT GEMM, fp16 MFMA: C[m][n] = sum_k A[m][k]*B[n][k].
// BK=32, ring-4 LDS buffers (128 KiB), prefetch distance 2, counted vmcnt(4).
// Per tile: all 12 ds_read_b128 issued up front (order pinned), lgkmcnt(4)
// covers cluster-0 operands; cluster-1's reads (a4..a7) complete in the
// shadow of cluster 0's 16 MFMAs -> no exposed LDS stall for half 2.
// XOR-swizzled LDS via pre-swizzled global source (linear gload_lds dest).
// 512 threads = 8 waves (2M x 4N), per-wave 128x64 out, acc f32x4[8][4].
// EPI: 0 = fp16 C[m][n]*cs; 1 = fp16 transposed C[n][m]*cs; 2 = fp32*cs.
// ---------------------------------------------------------------------------
template<int EPI>
__global__ __launch_bounds__(512, 2)
void gemm8(const u16* __restrict__ A, const u16* __restrict__ B,
           void* __restrict__ Cv, int K, int ldc, float cscale,
           long long sA, long long sB, long long sC)
{
  extern __shared__ char smem[];            // 131072 B: A [0,64K), B [64K,128K)
  const int tid  = threadIdx.x;
  const int lane = tid & 63;
  const int wid  = tid >> 6;
  const int wm   = wid >> 2;                // 0..1
  const int wn   = wid & 3;                 // 0..3

  // XCD-bijective swizzle of flat block id within z-slice (nwg % 8 == 0)
  const int gx  = gridDim.x;
  const int nwg = gx * gridDim.y;
  int f = blockIdx.y * gx + blockIdx.x;
  f = (f & 7) * (nwg >> 3) + (f >> 3);
  const int brow = (f / gx) << 8;
  const int bcol = (f % gx) << 8;
  const int z    = blockIdx.z;

  const u16* Ab = A + (size_t)z * sA;
  const u16* Bb = B + (size_t)z * sB;

  // staging: thread t supplies LDS-linear bytes t*16; global src pre-swizzled:
  // row = 2*(t>>3) + ((t>>2)&1)  (+128 per 2nd issue), k8 = (t&3) ^ ((t>>3)&3)
  const int srow = ((tid >> 3) << 1) | ((tid >> 2) & 1);
  const int sk8  = (tid & 3) ^ ((tid >> 3) & 3);
  const u16* gA0 = Ab + (size_t)(brow + srow) * K + sk8 * 8;
  const u16* gA1 = gA0 + (size_t)128 * K;
  const u16* gB0 = Bb + (size_t)(bcol + srow) * K + sk8 * 8;
  const u16* gB1 = gB0 + (size_t)128 * K;

  char* ldsAw = smem + tid * 16;            // linear write dest (A region)
  char* ldsBw = ldsAw + 65536;              // B region

  // read side: byte(r,k8) = (r>>1)*128 + ((k8 ^ ((r>>1)&3))<<4) + ((r&1)<<6)
  const int l15 = lane & 15;
  const int lanepart = ((l15 >> 1) << 7) |
                       ((((lane >> 4) ^ ((l15 >> 1) & 3))) << 4) |
                       ((lane & 1) << 6);
  const char* ldsA = smem + (wm << 13) + lanepart;           // + wm*8192
  const char* ldsB = smem + 65536 + (wn << 12) + lanepart;   // + wn*4096

  f32x4 acc[8][4];
  #pragma unroll
  for (int i = 0; i < 8; ++i)
    #pragma unroll
    for (int j = 0; j < 4; ++j) acc[i][j] = (f32x4){0.f, 0.f, 0.f, 0.f};

#define DS_A(BUF, MH, MR) (*(const f16x8*)(ldsA + (BUF)*16384 + (MH)*4096 + (MR)*1024))
#define DS_B(BUF, NR)     (*(const f16x8*)(ldsB + (BUF)*16384 + (NR)*1024))

#define MFMA4(AM, AV) \
  acc[AM][0] = __builtin_amdgcn_mfma_f32_16x16x32_f16(AV, b0, acc[AM][0], 0, 0, 0); \
  acc[AM][1] = __builtin_amdgcn_mfma_f32_16x16x32_f16(AV, b1, acc[AM][1], 0, 0, 0); \
  acc[AM][2] = __builtin_amdgcn_mfma_f32_16x16x32_f16(AV, b2, acc[AM][2], 0, 0, 0); \
  acc[AM][3] = __builtin_amdgcn_mfma_f32_16x16x32_f16(AV, b3, acc[AM][3], 0, 0, 0);

#define TILE(BUF, IBUF, DOISS, LASTT) do {                                    \
    if (LASTT) { asm volatile("s_waitcnt vmcnt(0)" ::: "memory"); }           \
    else       { asm volatile("s_waitcnt vmcnt(4)" ::: "memory"); }           \
    __builtin_amdgcn_s_barrier();                                             \
    if (DOISS) {                                                              \
      gload16(gA0, ldsAw + (IBUF)*16384);                                     \
      gload16(gA1, ldsAw + (IBUF)*16384 + 8192);                              \
    }                                                                         \
    /* cluster-0 operands: 8 ds_read_b128 */                                  \
    f16x8 b0 = DS_B(BUF,0), b1 = DS_B(BUF,1), b2 = DS_B(BUF,2), b3 = DS_B(BUF,3); \
    f16x8 a0 = DS_A(BUF,0,0), a1 = DS_A(BUF,0,1), a2 = DS_A(BUF,0,2), a3 = DS_A(BUF,0,3); \
    __builtin_amdgcn_sched_barrier(0);   /* pin: first 8 issued before next 4 */ \
    /* cluster-1 operands: 4 ds_read_b128, complete under cluster-0 MFMA */   \
    f16x8 a4 = DS_A(BUF,1,0), a5 = DS_A(BUF,1,1), a6 = DS_A(BUF,1,2), a7 = DS_A(BUF,1,3); \
    asm volatile("s_waitcnt lgkmcnt(4)" ::: "memory");                        \
    __builtin_amdgcn_sched_barrier(0);                                        \
    __builtin_amdgcn_s_setprio(1);                                            \
    MFMA4(0, a0) MFMA4(1, a1) MFMA4(2, a2) MFMA4(3, a3)                       \
    __builtin_amdgcn_s_setprio(0);                                            \
    if (DOISS) {                                                              \
      gload16(gB0, ldsBw + (IBUF)*16384);                                     \
      gload16(gB1, ldsBw + (IBUF)*16384 + 8192);                              \
      gA0 += 32; gA1 += 32; gB0 += 32; gB1 += 32;                             \
    }                                                                         \
    asm volatile("s_waitcnt lgkmcnt(0)" ::: "memory");                        \
    __builtin_amdgcn_sched_barrier(0);                                        \
    __builtin_amdgcn_s_barrier();                                             \
    __builtin_amdgcn_s_setprio(1);                                            \
    MFMA4(4, a4) MFMA4(5, a5) MFMA4(6, a6) MFMA4(7, a7)                       \
    __builtin_amdgcn_s_setprio(0);                                            \
  } while (0)

  // prologue: stage tiles 0 and 1 (issue order per tile: A,A,B,B)
  gload16(gA0, ldsAw);          gload16(gA1, ldsAw + 8192);
  gload16(gB0, ldsBw);          gload16(gB1, ldsBw + 8192);
  gA0 += 32; gA1 += 32; gB0 += 32; gB1 += 32;
  gload16(gA0, ldsAw + 16384);  gload16(gA1, ldsAw + 16384 + 8192);
  gload16(gB0, ldsBw + 16384);  gload16(gB1, ldsBw + 16384 + 8192);
  gA0 += 32; gA1 += 32; gB0 += 32; gB1 += 32;

  const int NT4 = K >> 7;                   // (K/32)/4, K multiple of 128
  for (int it = 0; it < NT4; ++it) {
    const bool lst = (it == NT4 - 1);
    TILE(0, 2, true,  false);
    TILE(1, 3, true,  false);
    TILE(2, 0, !lst,  false);
    TILE(3, 1, !lst,  lst);
  }

#undef TILE
#undef MFMA4
#undef DS_A
#undef DS_B

  // C/D layout: col = lane&15, row = (lane>>4)*4 + reg
  const float scv = cscale;
  const int cr0 = brow + (wm << 7) + ((lane >> 4) << 2);
  const int cc0 = bcol + (wn << 6) + l15;

  if constexpr (EPI == 0) {                 // fp16 store
    u16* C = (u16*)Cv + (size_t)z * sC;
    #pragma unroll
    for (int am = 0; am < 8; ++am) {
      const int r = cr0 + am * 16;
      #pragma unroll
      for (int an = 0; an < 4; ++an) {
        const int c = cc0 + an * 16;
        #pragma unroll
        for (int j = 0; j < 4; ++j)
          C[(size_t)(r + j) * ldc + c] = f2h(acc[am][an][j] * scv);
      }
    }
  } else if constexpr (EPI == 1) {          // fp16 transposed store C[n][m]
    u16* C = (u16*)Cv + (size_t)z * sC;
    #pragma unroll
    for (int am = 0; am < 8; ++am) {
      const int r = cr0 + am * 16;
      #pragma unroll
      for (int an = 0; an < 4; ++an) {
        const int c = cc0 + an * 16;
        ushort4 pk;
        pk.x = f2h(acc[am][an][0] * scv);
        pk.y = f2h(acc[am][an][1] * scv);
        pk.z = f2h(acc[am][an][2] * scv);
        pk.w = f2h(acc[am][an][3] * scv);
        *(ushort4*)&C[(size_t)c * ldc + r] = pk;
      }
    }
  } else {                                  // fp32 store
    float* C = (float*)Cv + (size_t)z * sC;
    #pragma unroll
    for (int am = 0; am < 8; ++am) {
      const int r = cr0 + am * 16;
      #pragma unroll
      for (int an = 0; an < 4; ++an) {
        const int c = cc0 + an * 16;
        #pragma unroll
        for (int j = 0; j < 4; ++j)
          C[(size_t)(r + j) * ldc + c] = acc[am][an][j] * scv;
      }
    }
  }
}

// ---------------------------------------------------------------------------
// bitlinear scale: two-stage deterministic mean(|w|)
// ---------------------------------------------------------------------------
__global__ __launch_bounds__(256)
void abssum_partial(const float* __restrict__ w0, const float* __restrict__ w1,
                    const float* __restrict__ w2, const float* __restrict__ w3,
                    float* __restrict__ part)
{
  const float* w = (blockIdx.y==0)?w0:(blockIdx.y==1)?w1:(blockIdx.y==2)?w2:w3;
  float s = 0.f;
  const int N4 = WELEMS/4;
  for (int i = blockIdx.x*256 + threadIdx.x; i < N4; i += 256*256) {
    float4 v = ((const float4*)w)[i];
    s += fabsf(v.x)+fabsf(v.y)+fabsf(v.z)+fabsf(v.w);
  }
  #pragma unroll
  for (int o=32;o;o>>=1) s += __shfl_xor(s,o);
  __shared__ float r[4];
  if ((threadIdx.x&63)==0) r[threadIdx.x>>6] = s;
  __syncthreads();
  if (threadIdx.x==0) part[blockIdx.y*256 + blockIdx.x] = (r[0]+r[1])+(r[2]+r[3]);
}

__global__ __launch_bounds__(256)
void scale_final(const float* __restrict__ part, float* __restrict__ scales)
{
  float s = part[blockIdx.x*256 + threadIdx.x];
  #pragma unroll
  for (int o=32;o;o>>=1) s += __shfl_xor(s,o);
  __shared__ float r[4];
  if ((threadIdx.x&63)==0) r[threadIdx.x>>6] = s;
  __syncthreads();
  if (threadIdx.x==0) scales[blockIdx.x] = ((r[0]+r[1])+(r[2]+r[3])) * (1.f/(float)WELEMS);
}

// ternary quant + fp16 dequant: w -> rint(clip(w/(s+eps)))*s, stored fp16
__global__ __launch_bounds__(256)
void dequant_w(const float* __restrict__ w0, const float* __restrict__ w1,
               const float* __restrict__ w2, const float* __restrict__ w3,
               const float* __restrict__ scales, u16* __restrict__ out)
{
  const int wi = blockIdx.y;
  const float* w = (wi==0)?w0:(wi==1)?w1:(wi==2)?w2:w3;
  u16* o = out + (size_t)wi * WELEMS;
  const float scv = scales[wi];
  const float inv = 1.f/(scv + 1e-5f);
  const int i0 = (blockIdx.x*256 + threadIdx.x)*8;
  float4 a = *(const float4*)(w + i0);
  float4 b = *(const float4*)(w + i0 + 4);
  float t[8] = {a.x,a.y,a.z,a.w,b.x,b.y,b.z,b.w};
  union { uint4 v; u16 h[8]; } r;
  #pragma unroll
  for (int j=0;j<8;++j){
    float x = t[j]*inv;
    x = fminf(fmaxf(x,-1.f),1.f);
    r.h[j] = f2h(rintf(x)*scv);
  }
  *(uint4*)(o + i0) = r.v;
}

__global__ __launch_bounds__(256)
void cast_f16(const float* __restrict__ x, u16* __restrict__ o)
{
  const int i0 = (blockIdx.x*256 + threadIdx.x)*8;
  float4 a = *(const float4*)(x + i0);
  float4 b = *(const float4*)(x + i0 + 4);
  float t[8] = {a.x,a.y,a.z,a.w,b.x,b.y,b.z,b.w};
  union { uint4 v; u16 h[8]; } r;
  #pragma unroll
  for (int j=0;j<8;++j) r.h[j] = f2h(t[j]);
  *(uint4*)(o + i0) = r.v;
}

// in-place RoPE on fp16 Q and K (pair d, d+64 within each 128-dim chunk)
__global__ __launch_bounds__(256)
void rope_qk(u16* __restrict__ Q, u16* __restrict__ K,
             const float* __restrict__ cosb, const float* __restrict__ sinb)
{
  const uint32_t idx = blockIdx.x*256 + threadIdx.x;   // < 2*4096*16*64
  const int d   = idx & 63;
  const int h16 = (idx >> 6) & 15;
  const int s   = (idx >> 10) & (S_-1);
  const int b   = idx >> 22;
  const size_t base = ((size_t)b*S_ + s)*H_ + h16*128 + d;
  const int ci = s*128 + d;
  const float c0 = cosb[ci], c1 = cosb[ci+64];
  const float s0 = sinb[ci], s1 = sinb[ci+64];
  const float q0 = h2f(Q[base]), q1 = h2f(Q[base+64]);
  Q[base]    = f2h(q0*c0 - q1*s0);
  Q[base+64] = f2h(q1*c1 + q0*s1);
  const float k0 = h2f(K[base]), k1 = h2f(K[base+64]);
  K[base]    = f2h(k0*c0 - k1*s0);
  K[base+64] = f2h(k1*c1 + k0*s1);
}

// row softmax over S_=4096, in place on fp16 scores (scale already applied);
// adds mask, writes fp16 probs
__global__ __launch_bounds__(256)
void softmax_h(u16* __restrict__ P, const float* __restrict__ mask)
{
  const int row = blockIdx.x;               // 0..B_*S_-1
  const int q   = row & (S_-1);
  u16* prow = P + (size_t)row * S_;
  const float* mrow = mask + (size_t)q * S_;
  const int tid  = threadIdx.x;
  const int lane = tid & 63;
  const int base = tid * 16;

  union { uint4 v[2]; u16 h[16]; } sv;
  sv.v[0] = *(const uint4*)(prow + base);
  sv.v[1] = *(const uint4*)(prow + base + 8);
  float mk[16];
  #pragma unroll
  for (int j=0;j<4;++j) ((float4*)mk)[j] = *(const float4*)(mrow + base + 4*j);

  float v[16];
  #pragma unroll
  for (int i=0;i<16;++i) v[i] = h2f(sv.h[i]) + mk[i];

  float mx = v[0];
  #pragma unroll
  for (int i=1;i<16;++i) mx = fmaxf(mx, v[i]);
  #pragma unroll
  for (int o=32;o;o>>=1) mx = fmaxf(mx, __shfl_xor(mx, o));
  __shared__ float red[8];
  if (lane==0) red[tid>>6] = mx;
  __syncthreads();
  mx = fmaxf(fmaxf(red[0],red[1]), fmaxf(red[2],red[3]));

  float e[16]; float sm = 0.f;
  #pragma unroll
  for (int i=0;i<16;++i){ e[i] = __expf(v[i]-mx); sm += e[i]; }
  #pragma unroll
  for (int o=32;o;o>>=1) sm += __shfl_xor(sm, o);
  if (lane==0) red[4 + (tid>>6)] = sm;
  __syncthreads();
  sm = (red[4]+red[5])+(red[6]+red[7]);
  const float inv = 1.f/sm;

  union { uint4 v[2]; u16 h[16]; } ov;
  #pragma unroll
  for (int i=0;i<16;++i) ov.h[i] = f2h(e[i]*inv);
  *(uint4*)(prow + base)     = ov.v[0];
  *(uint4*)(prow + base + 8) = ov.v[1];
}

__global__ void fill_f32(float* p, float v, int n) {
  int i = blockIdx.x*256 + threadIdx.x;
  if (i < n) p[i] = v;
}

// ---------------------------------------------------------------------------
extern "C" void kernel_launch(void* const* d_in, const int* in_sizes, int n_in,
                              void* d_out, int out_size, void* d_ws, size_t ws_size,
                              hipStream_t stream)
{
  const float* hs   = (const float*)d_in[0];
  const float* mask = (const float*)d_in[1];
  const float* cosb = (const float*)d_in[2];
  const float* sinb = (const float*)d_in[3];
  const float* wq   = (const float*)d_in[4];
  const float* wk   = (const float*)d_in[5];
  const float* wv   = (const float*)d_in[6];
  const float* wo   = (const float*)d_in[7];

  // ws layout, 128 MiB exactly (lifetime aliasing):
  //   Wh [0,32M)   : 4 pre-scaled ternary weights, fp16    (live whole call)
  //   Xh [32,64M)  : hidden_states fp16                    (dead after Vt)
  //   Qh [64,96M)  : Q fp16 -> AO (PV output) per batch
  //   Kh [96,128M) : K fp16 -> Vt[b][h][tok] per batch
  // d_out: part/scales (head, pre-GEMM) -> fp16 scores/probs both batches
  //        (64 MiB exactly) -> final fp32 output.
  char* w = (char*)d_ws;
  const size_t SZ = (size_t)M2_ * H_ * 2;   // 32 MiB
  u16* Wh = (u16*)(w);
  u16* Xh = (u16*)(w + SZ);
  u16* Qh = (u16*)(w + 2*SZ);
  u16* Kh = (u16*)(w + 3*SZ);
  u16* AO = Qh;                              // alias after QK^T
  u16* Vt = Kh;                              // alias after QK^T
  float* part   = (float*)d_out;             // dead before scores written
  float* scales = part + 1024;
  u16* P  = (u16*)d_out;                     // fp16 scores/probs, both batches

  const size_t need = 4*SZ;                  // 134,217,728 B
  if (ws_size < need || out_size != M2_*H_) {
    float v = (out_size != M2_*H_) ? 2.0e9f : (float)ws_size;
    fill_f32<<<dim3((out_size+255)/256), dim3(256), 0, stream>>>((float*)d_out, v, out_size);
    return;
  }

  dim3 blk(256), gblk(512);
  const size_t QOFF = (size_t)S_*H_;         // per-batch elems
  const float qksc = 0.08838834764831845f;   // 1/sqrt(128)

  abssum_partial<<<dim3(256,4), blk, 0, stream>>>(wq,wk,wv,wo, part);
  scale_final  <<<dim3(4),     blk, 0, stream>>>(part, scales);
  dequant_w    <<<dim3(WELEMS/(256*8),4), blk, 0, stream>>>(wq,wk,wv,wo, scales, Wh);
  cast_f16     <<<dim3((M2_*H_)/(256*8)), blk, 0, stream>>>(hs, Xh);

  // Q = X @ Wq^T ; K = X @ Wk^T   (M=8192, N=2048, K=2048)
  gemm8<0><<<dim3(8,32,1), gblk, 131072, stream>>>(Xh, Wh,        Qh, H_, H_, 1.f, 0,0,0);
  gemm8<0><<<dim3(8,32,1), gblk, 131072, stream>>>(Xh, Wh+WELEMS, Kh, H_, H_, 1.f, 0,0,0);

  rope_qk<<<dim3((B_*S_*16*64)/256), blk, 0, stream>>>(Qh, Kh, cosb, sinb);

  // scores = (Q @ K^T)/sqrt(hd), fp16, per batch: M=N=4096, K=2048
  gemm8<0><<<dim3(16,16,2), gblk, 131072, stream>>>(Qh, Kh, P, H_, S_, qksc,
      (long long)QOFF, (long long)QOFF, (long long)S_*S_);

  softmax_h<<<dim3(B_*S_), blk, 0, stream>>>(P, mask);

  // Vt = (X_b @ Wv^T)^T -> [b][h][tok] into Kh (dead): M=4096, N=2048, K=2048
  gemm8<1><<<dim3(8,16,2), gblk, 131072, stream>>>(Xh, Wh+2*WELEMS, Vt, H_, S_, 1.f,
      (long long)QOFF, 0, (long long)H_*S_);

  // AO_b = probs @ V = P[q,k]*Vt[h,k] -> Qh (dead): M=4096, N=2048, K=4096
  gemm8<0><<<dim3(8,16,2), gblk, 131072, stream>>>(P, Vt, AO, S_, H_, 1.f,
      (long long)S_*S_, (long long)H_*S_, (long long)QOFF);

  // out = AO @ Wo^T (fp32): M=8192, N=2048, K=2048
  gemm8<2><<<dim3(8,32,1), gblk, 131072, stream>>>(AO, Wh+3*WELEMS, d_out, H_, H_, 1.f, 0,0,0);
}